// Round 18
// baseline (591.642 us; speedup 1.0000x reference)
//
#include <hip/hip_runtime.h>
#include <cstdint>
#include <cstddef>

#define B_ 8
#define S_ 1024
#define D_ 512
#define H_ 8
#define DFF_ 2048
#define STEPS_ 6
#define M_ (B_*S_)   // 8192 tokens

typedef unsigned short u16;
typedef u16   u16x8 __attribute__((ext_vector_type(8)));
typedef short s16x8 __attribute__((ext_vector_type(8)));
typedef float f32x4 __attribute__((ext_vector_type(4)));
typedef float f32x16 __attribute__((ext_vector_type(16)));

__device__ __forceinline__ u16 f2b(float f){
  union { float f; unsigned u; } v; v.f = f;
  unsigned r = v.u + 0x7fffu + ((v.u >> 16) & 1u);
  return (u16)(r >> 16);
}
__device__ __forceinline__ float b2f(u16 u){
  union { unsigned u; float f; } v; v.u = ((unsigned)u) << 16;
  return v.f;
}
__device__ __forceinline__ unsigned cvtpk(float lo, float hi){
  unsigned r;
  asm("v_cvt_pk_bf16_f32 %0, %1, %2" : "=v"(r) : "v"(lo), "v"(hi));
  return r;
}
__device__ __forceinline__ void gload16(const void* g, void* l){
  __builtin_amdgcn_global_load_lds(
    (const __attribute__((address_space(1))) void*)g,
    (__attribute__((address_space(3))) void*)l, 16, 0, 0);
}
__device__ __forceinline__ float wred_sum(float v){
  #pragma unroll
  for (int m = 1; m < 64; m <<= 1) v += __shfl_xor(v, m, 64);
  return v;
}

// ---------------- prep: st = x, stb = bf16(x), initial halting state ----------------
__global__ __launch_bounds__(256) void prep_kernel(const float* __restrict__ x,
    const float* __restrict__ aw, const float* __restrict__ ab,
    float* __restrict__ st, u16* __restrict__ stb,
    float* __restrict__ hp, float* __restrict__ rem, float* __restrict__ uw){
  int tid = threadIdx.x; int l = tid & 63; int w = tid >> 6;
  size_t i = (size_t)blockIdx.x*256 + tid;     // one wave = one row
  const float4* xp = (const float4*)x + i*2;
  float4 a = xp[0], b = xp[1];
  ((float4*)st)[i*2]   = a;
  ((float4*)st)[i*2+1] = b;
  u16x8 o;
  o[0]=f2b(a.x); o[1]=f2b(a.y); o[2]=f2b(a.z); o[3]=f2b(a.w);
  o[4]=f2b(b.x); o[5]=f2b(b.y); o[6]=f2b(b.z); o[7]=f2b(b.w);
  ((u16x8*)stb)[i] = o;
  const float4* wp = (const float4*)aw + (size_t)l*2;
  float4 w0 = wp[0], w1 = wp[1];
  float d = a.x*w0.x + a.y*w0.y + a.z*w0.z + a.w*w0.w
          + b.x*w1.x + b.y*w1.y + b.z*w1.z + b.w*w1.w;
  d = wred_sum(d);
  if (l == 0){
    int row = blockIdx.x*4 + w;
    float t = d + ab[0];
    float p = 1.f / (1.f + expf(-t));
    // reference step with h=0, r=0
    float nh  = (p > 0.99f) ? 1.f : 0.f;
    float st2 = 1.f - nh;
    float h = p*st2;
    float r = nh*(1.f - h);
    h += nh*r;
    hp[row] = h; rem[row] = r;
    uw[row] = p*st2 + nh*r;
  }
}

// ---------------- tiled transpose-cast: W[K][N] f32 -> Wt[N][K] bf16, row-scaled ----------------
__global__ __launch_bounds__(256) void tcast_kernel(const float* __restrict__ W,
    u16* __restrict__ Wt, int K, int N, const float* __restrict__ scale){
  __shared__ u16 T[64*66];
  int tid = threadIdx.x;
  int nbt = N >> 6;
  int k0 = (blockIdx.x / nbt) << 6, n0 = (blockIdx.x % nbt) << 6;
  int r = tid >> 2, c4 = tid & 3;
  float sc = scale ? scale[k0 + r] : 1.f;
  const float* src = W + (size_t)(k0 + r)*N + n0 + c4*16;
  #pragma unroll
  for (int q = 0; q < 2; q++){
    float4 f0 = ((const float4*)src)[q*2], f1 = ((const float4*)src)[q*2+1];
    u16x8 t;
    t[0]=f2b(f0.x*sc); t[1]=f2b(f0.y*sc); t[2]=f2b(f0.z*sc); t[3]=f2b(f0.w*sc);
    t[4]=f2b(f1.x*sc); t[5]=f2b(f1.y*sc); t[6]=f2b(f1.z*sc); t[7]=f2b(f1.w*sc);
    *(u16x8*)&T[r*66 + c4*16 + q*8] = t;
  }
  __syncthreads();
  int n = tid >> 2;
  #pragma unroll
  for (int t2 = 0; t2 < 2; t2++){
    int sc2 = (tid & 3) + t2*4;
    u16x8 o;
    #pragma unroll
    for (int j = 0; j < 8; j++) o[j] = T[(sc2*8 + j)*66 + n];
    *(u16x8*)&Wt[(size_t)(n0 + n)*K + k0 + sc2*8] = o;
  }
}

// packb + freeze-flag init
__global__ void packb_kernel(const float* __restrict__ bq, const float* __restrict__ bk,
                             const float* __restrict__ bv, float* __restrict__ bqkv,
                             unsigned* __restrict__ flags){
  int i = blockIdx.x*256 + threadIdx.x;
  if (i < 512)       bqkv[i] = bq[i];
  else if (i < 1024) bqkv[i] = bk[i-512];
  else if (i < 1536) bqkv[i] = bv[i-1024];
  if (blockIdx.x == 0 && threadIdx.x < 256){
    int t = threadIdx.x;
    // [0..63] act par0, [64..127] act par1, [128..191] chg par0, [192..255] chg par1
    flags[t] = (t < 64 || (t >= 128 && t < 192)) ? 1u : 0u;
  }
}

// ---------------- G/C precompute (coalesced 2-stage) ----------------
__global__ __launch_bounds__(256) void gcpart_kernel(const float* __restrict__ W,
    const float* __restrict__ g, const float* __restrict__ be,
    float* __restrict__ pg, float* __restrict__ pc, int N){
  int kb = blockIdx.x, cb = blockIdx.y, t = threadIdx.x;
  __shared__ float gs[64], bs[64];
  if (t < 64){ gs[t] = g[kb*64 + t]; bs[t] = be[kb*64 + t]; }
  __syncthreads();
  int col = cb*256 + t;
  float ag = 0.f, ac = 0.f;
  #pragma unroll 8
  for (int k = 0; k < 64; k++){
    float w = W[(size_t)(kb*64 + k)*N + col];
    ag = fmaf(gs[k], w, ag);
    ac = fmaf(bs[k], w, ac);
  }
  pg[(size_t)kb*N + col] = ag;
  pc[(size_t)kb*N + col] = ac;
}

__global__ __launch_bounds__(256) void gcred_kernel(const float* __restrict__ pg,
    const float* __restrict__ pc, float* __restrict__ G, float* __restrict__ Cc,
    int np, int N){
  int col = blockIdx.x*256 + threadIdx.x;
  float sg = 0.f, sc = 0.f;
  for (int i = 0; i < np; i++){
    sg += pg[(size_t)i*N + col];
    sc += pc[(size_t)i*N + col];
  }
  G[col] = sg; Cc[col] = sc;
}

// ---------------- per-row stats reduce (+ optional next-step flag zeroing) ----------------
__global__ __launch_bounds__(256) void stats_kernel(const float2* __restrict__ parts,
    float2* __restrict__ stats, int np, float invD,
    const unsigned* __restrict__ tfact, unsigned* __restrict__ zeroA,
    unsigned* __restrict__ zeroB){
  if (zeroA && blockIdx.x == 0){
    int t = threadIdx.x;
    if (t < 64) zeroA[t] = 0u;
    else if (t < 128) zeroB[t-64] = 0u;
  }
  int tok = blockIdx.x*256 + threadIdx.x;
  if (!tfact[tok >> 7]) return;
  float s = 0.f, q = 0.f;
  for (int i = 0; i < np; i++){
    float2 p = parts[(size_t)i*M_ + tok];
    s += p.x; q += p.y;
  }
  float mu = s*invD;
  float var = q*invD - mu*mu;
  stats[tok] = make_float2(mu, rsqrtf(fmaxf(var, 0.f) + 1e-6f));
}

// ---------------- 128x128 GEMM, BK=64, 8 waves (512 thr), double-buffered ----------------
// EPI 1: qkv. Q-blocks (n0<512) gate on act[tm]; K/V blocks gate on chg[tm] && batch-active.
// EPI 3: wo:  y = acc + bias + resid(bf16 stb); bf16 out + row partials (np=16); skip by act
// EPI 4: ffn1: relu(LN-affine); bf16 out + partials (np=64); skip by act
// EPI 5: ffn2: LN-affine; bf16 out; skip by act
template<int EPI>
__global__ __launch_bounds__(512, 4) void gemm128_kernel(
    const u16* __restrict__ A, const u16* __restrict__ Bt,
    const float* __restrict__ bias, void* __restrict__ C,
    int ntn, int K, int ldo, u16* __restrict__ vt,
    const float2* __restrict__ strow, const float* __restrict__ gvec,
    const float* __restrict__ cvec, float2* __restrict__ parts,
    const u16* __restrict__ resid16, const unsigned* __restrict__ tflag,
    const unsigned* __restrict__ actarr){
  __shared__ u16 Als[2][128*64];
  __shared__ u16 Bls[2][128*64];
  int tid = threadIdx.x, l = tid & 63, w = tid >> 6;   // w in [0,8)
  int hi = l >> 4, ln = l & 15;
  int wm = w >> 2, wn = w & 3;                 // 2M x 4N wave grid; wave out 64x32
  int nwg = gridDim.x;
  int bid = blockIdx.x;
  int swz = (bid & 7) * (nwg >> 3) + (bid >> 3);   // XCD-contiguous (nwg % 8 == 0)
  int tn = swz % ntn, tm = swz / ntn;
  int m0 = tm << 7, n0 = tn << 7;
  if (EPI == 1){
    if (n0 < 512){                             // Q: only for active q-tiles
      if (!actarr[tm]) return;
    } else {                                   // K/V: fresh + batch has active queries
      int b8 = (tm >> 3) << 3;
      unsigned ba = actarr[b8]   | actarr[b8+1] | actarr[b8+2] | actarr[b8+3]
                  | actarr[b8+4] | actarr[b8+5] | actarr[b8+6] | actarr[b8+7];
      if (!ba || !tflag[tm]) return;
    }
  } else {
    if (!tflag[tm]) return;                    // freeze skip (uniform)
  }
  int rl8 = l >> 3;
  int cg = (l & 7) ^ rl8;                      // pre-swizzled 16B chunk
  size_t aoff = (size_t)(m0 + w*8 + rl8)*K + cg*8;
  size_t boff = (size_t)(n0 + w*8 + rl8)*K + cg*8;
  int nt = K >> 6;

  f32x4 acc[4][2];
  #pragma unroll
  for (int i=0;i<4;i++)
    #pragma unroll
    for (int j=0;j<2;j++) acc[i][j] = (f32x4){0.f,0.f,0.f,0.f};

  // per buffer per thread: 2 A-loads + 2 B-loads; wave-load covers 8 rows x 64 cols
  #define G128(buf, kt) do { \
    size_t kof = (size_t)(kt)*64; \
    _Pragma("unroll") \
    for (int j = 0; j < 2; j++){ \
      gload16(A  + aoff + (size_t)j*64*K + kof, &Als[buf][(j*8 + w)*512]); \
      gload16(Bt + boff + (size_t)j*64*K + kof, &Bls[buf][(j*8 + w)*512]); \
    } } while(0)

  G128(0, 0);
  __syncthreads();

  for (int t = 0; t < nt; t++){
    int cur = t & 1;
    if (t+1 < nt) G128(cur^1, t+1);            // prefetch into the OTHER buffer
    s16x8 af[4][2], bf[2][2];
    #pragma unroll
    for (int mi=0;mi<4;mi++){
      int row = wm*64 + mi*16 + ln;
      #pragma unroll
      for (int kk=0;kk<2;kk++)
        af[mi][kk] = *(const s16x8*)&Als[cur][row*64 + (((kk*4+hi)^(row&7))*8)];
    }
    #pragma unroll
    for (int ni=0;ni<2;ni++){
      int row = wn*32 + ni*16 + ln;
      #pragma unroll
      for (int kk=0;kk<2;kk++)
        bf[ni][kk] = *(const s16x8*)&Bls[cur][row*64 + (((kk*4+hi)^(row&7))*8)];
    }
    #pragma unroll
    for (int mi=0;mi<4;mi++)
      #pragma unroll
      for (int ni=0;ni<2;ni++)
        #pragma unroll
        for (int kk=0;kk<2;kk++)
          acc[mi][ni] = __builtin_amdgcn_mfma_f32_16x16x32_bf16(af[mi][kk], bf[ni][kk], acc[mi][ni], 0,0,0);
    if (t+1 < nt) __syncthreads();
  }
  #undef G128

  if (EPI == 1){
    if (n0 >= 1024){
      #pragma unroll
      for (int mi=0;mi<4;mi++){
        int row0 = m0 + wm*64 + mi*16 + hi*4;
        int b = row0 >> 10, s0 = row0 & 1023;
        #pragma unroll
        for (int ni=0;ni<2;ni++){
          int vcol = (n0 - 1024) + wn*32 + ni*16 + ln;
          int h = vcol >> 6, d = vcol & 63;
          float bc = bias[1024 + vcol];
          uint2 pk;
          pk.x = cvtpk(acc[mi][ni][0] + bc, acc[mi][ni][1] + bc);
          pk.y = cvtpk(acc[mi][ni][2] + bc, acc[mi][ni][3] + bc);
          *(uint2*)&vt[((size_t)((b*8 + h)*64 + d))*1024 + s0] = pk;
        }
      }
      return;
    }
    float qs = (n0 < 512) ? 0.125f : 1.0f;     // fold softmax scale into Q
    #pragma unroll
    for (int mi=0;mi<4;mi++){
      int row0 = m0 + wm*64 + mi*16 + hi*4;
      #pragma unroll
      for (int ni=0;ni<2;ni++){
        int col = n0 + wn*32 + ni*16 + ln;
        float bc = bias[col];
        #pragma unroll
        for (int r=0;r<4;r++)
          ((u16*)C)[(size_t)(row0+r)*ldo + col] = f2b((acc[mi][ni][r] + bc)*qs);
      }
    }
    return;
  }

  if (EPI == 3){
    float bv[2];
    #pragma unroll
    for (int ni=0;ni<2;ni++) bv[ni] = bias[n0 + wn*32 + ni*16 + ln];
    #pragma unroll
    for (int mi=0;mi<4;mi++){
      int row0 = m0 + wm*64 + mi*16 + hi*4;
      #pragma unroll
      for (int r=0;r<4;r++){
        int row = row0 + r;
        float s = 0.f, q = 0.f;
        #pragma unroll
        for (int ni=0;ni<2;ni++){
          int col = n0 + wn*32 + ni*16 + ln;
          float v = acc[mi][ni][r] + bv[ni] + b2f(resid16[(size_t)row*ldo + col]);
          ((u16*)C)[(size_t)row*ldo + col] = f2b(v);
          s += v; q += v*v;
        }
        #pragma unroll
        for (int msk=1;msk<16;msk<<=1){ s += __shfl_xor(s,msk,64); q += __shfl_xor(q,msk,64); }
        if (ln == 0) parts[(size_t)(tn*4 + wn)*M_ + row] = make_float2(s, q);
      }
    }
    return;
  }

  // EPI 4 / 5
  {
    float gv[2], cv[2];
    #pragma unroll
    for (int ni=0;ni<2;ni++){
      int col = n0 + wn*32 + ni*16 + ln;
      gv[ni] = gvec[col];
      cv[ni] = cvec[col] + bias[col];
    }
    #pragma unroll
    for (int mi=0;mi<4;mi++){
      int row0 = m0 + wm*64 + mi*16 + hi*4;
      #pragma unroll
      for (int r=0;r<4;r++){
        int row = row0 + r;
        float2 sr = strow[row];
        float rmu = sr.y * sr.x;
        float s = 0.f, q = 0.f;
        #pragma unroll
        for (int ni=0;ni<2;ni++){
          int col = n0 + wn*32 + ni*16 + ln;
          float v = sr.y*acc[mi][ni][r] - rmu*gv[ni] + cv[ni];
          if (EPI == 4) v = fmaxf(v, 0.f);
          ((u16*)C)[(size_t)row*ldo + col] = f2b(v);
          s += v; q += v*v;
        }
        if (EPI == 4){
          #pragma unroll
          for (int msk=1;msk<16;msk<<=1){ s += __shfl_xor(s,msk,64); q += __shfl_xor(q,msk,64); }
          if (ln == 0) parts[(size_t)(tn*4 + wn)*M_ + row] = make_float2(s, q);
        }
      }
    }
  }
}

// ---------------- flash attention, 32x32 MFMA, swapped QK^T, permlane P-redistribute ----------------
__global__ __launch_bounds__(256) void attn_kernel(const u16* __restrict__ qkv,
                                                   const u16* __restrict__ vt,
                                                   u16* __restrict__ ctx,
                                                   const unsigned* __restrict__ tfact){
  __shared__ u16 Ks[2][64*64];
  __shared__ u16 Vs[2][64*64];
  int tid = threadIdx.x, l = tid & 63, w = tid >> 6;
  int q5 = l & 31, hi2 = l >> 5;
  int orig = ((blockIdx.x & 7) << 6) | (blockIdx.x >> 3);   // XCD-contiguous: one b per XCD
  int qt = orig & 7, h = (orig >> 3) & 7, b = orig >> 6;
  if (!tfact[b*8 + qt]) return;                             // freeze skip (uniform)
  size_t rowbase = (size_t)b * S_;

  int qrow = qt*128 + w*32 + q5;
  s16x8 bq[4];
  #pragma unroll
  for (int dk = 0; dk < 4; dk++)
    bq[dk] = *(const s16x8*)&qkv[(rowbase + qrow)*1536 + h*64 + dk*16 + hi2*8];

  int rl = l >> 3;
  int cg = (l & 7) ^ rl;
  const u16* kb = qkv + rowbase*1536 + 512 + h*64 + cg*8;
  const u16* vb = vt + (size_t)((b*8 + h)*64)*1024 + cg*8;

  f32x16 o[2];
  #pragma unroll
  for (int mt = 0; mt < 2; mt++)
    #pragma unroll
    for (int r = 0; r < 16; r++) o[mt][r] = 0.f;
  float l_ = 0.f;

  #define STAGE(buf, kt) do { \
    _Pragma("unroll") \
    for (int r2 = 0; r2 < 2; r2++){ \
      int rr = r2*32 + w*8; \
      gload16(kb + (size_t)((kt)*64 + rr + rl)*1536, &Ks[buf][rr*64]); \
      gload16(vb + (size_t)(rr + rl)*1024 + (kt)*64, &Vs[buf][rr*64]); \
    } } while(0)

  STAGE(0, 0);
  STAGE(1, 1);
  asm volatile("s_waitcnt vmcnt(4)" ::: "memory");
  __builtin_amdgcn_s_barrier();
  __builtin_amdgcn_sched_barrier(0);

  for (int kt = 0; kt < 16; kt++){
    int cur = kt & 1;
    s16x8 ak[2][4], av[2][4];
    #pragma unroll
    for (int mt = 0; mt < 2; mt++){
      int r0 = mt*32 + q5;
      int sw = r0 & 7;
      #pragma unroll
      for (int dk = 0; dk < 4; dk++)
        ak[mt][dk] = *(const s16x8*)&Ks[cur][r0*64 + (((2*dk + hi2) ^ sw)*8)];
      #pragma unroll
      for (int ks = 0; ks < 4; ks++)
        av[mt][ks] = *(const s16x8*)&Vs[cur][r0*64 + (((2*ks + hi2) ^ sw)*8)];
    }
    asm volatile("s_waitcnt lgkmcnt(0)" ::: "memory");
    __builtin_amdgcn_sched_barrier(0);
    __builtin_amdgcn_s_barrier();
    __builtin_amdgcn_sched_barrier(0);
    if (kt < 14) STAGE(cur, kt+2);

    f32x16 sacc[2];
    #pragma unroll
    for (int mt = 0; mt < 2; mt++){
      f32x16 acc;
      #pragma unroll
      for (int r = 0; r < 16; r++) acc[r] = 0.f;
      #pragma unroll
      for (int dk = 0; dk < 4; dk++)
        acc = __builtin_amdgcn_mfma_f32_32x32x16_bf16(ak[mt][dk], bq[dk], acc, 0,0,0);
      sacc[mt] = acc;
    }

    float p[2][16];
    float rs = 0.f;
    #pragma unroll
    for (int mt = 0; mt < 2; mt++)
      #pragma unroll
      for (int r = 0; r < 16; r++){
        float e = __expf(sacc[mt][r]);
        p[mt][r] = e; rs += e;
      }
    rs += __shfl_xor(rs, 32, 64);
    l_ += rs;

    unsigned wds[4][4];
    #pragma unroll
    for (int ks = 0; ks < 4; ks++){
      const int mt = ks >> 1, base = (ks & 1)*8;
      unsigned a0 = cvtpk(p[mt][base+0], p[mt][base+1]);
      unsigned b0 = cvtpk(p[mt][base+4], p[mt][base+5]);
      asm("v_permlane32_swap_b32 %0, %1" : "+v"(a0), "+v"(b0));
      unsigned a1 = cvtpk(p[mt][base+2], p[mt][base+3]);
      unsigned b1 = cvtpk(p[mt][base+6], p[mt][base+7]);
      asm("v_permlane32_swap_b32 %0, %1" : "+v"(a1), "+v"(b1));
      wds[ks][0] = a0; wds[ks][1] = a1; wds[ks][2] = b0; wds[ks][3] = b1;
    }

    #pragma unroll
    for (int ks = 0; ks < 4; ks++){
      union { unsigned u[4]; s16x8 v; } bp;
      bp.u[0] = wds[ks][0]; bp.u[1] = wds[ks][1];
      bp.u[2] = wds[ks][2]; bp.u[3] = wds[ks][3];
      #pragma unroll
      for (int mt = 0; mt < 2; mt++)
        o[mt] = __builtin_amdgcn_mfma_f32_32x32x16_bf16(av[mt][ks], bp.v, o[mt], 0,0,0);
    }

    if (kt < 15){
      if (kt < 14) asm volatile("s_waitcnt vmcnt(4)" ::: "memory");
      else         asm volatile("s_waitcnt vmcnt(0)" ::: "memory");
      __builtin_amdgcn_s_barrier();
      __builtin_amdgcn_sched_barrier(0);
    }
  }
  #undef STAGE

  __builtin_amdgcn_s_barrier();
  float inv = 1.f / l_;
  u16* ob = ((w < 2) ? (u16*)Ks : (u16*)Vs) + (w & 1)*2304;
  #pragma unroll
  for (int mt = 0; mt < 2; mt++)
    #pragma unroll
    for (int g = 0; g < 4; g++)
      #pragma unroll
      for (int p2 = 0; p2 < 2; p2++){
        unsigned wd = cvtpk(o[mt][g*4 + p2*2]*inv, o[mt][g*4 + p2*2 + 1]*inv);
        int d0 = mt*32 + g*8 + hi2*4 + p2*2;
        *(unsigned*)&ob[q5*72 + d0] = wd;
      }
  asm volatile("s_waitcnt lgkmcnt(0)" ::: "memory");
  __builtin_amdgcn_sched_barrier(0);
  int r2 = l >> 1, cb = (l & 1)*32;
  size_t row = rowbase + qt*128 + w*32 + r2;
  #pragma unroll
  for (int c = 0; c < 4; c++){
    uint4 v = *(uint4*)&ob[r2*72 + cb + c*8];
    *(uint4*)&ctx[row*512 + h*64 + cb + c*8] = v;
  }
}

// ---------------- LN2 + ACT mix + next-step halting update (4 rows / 256-thr block) ----------------
__global__ __launch_bounds__(256) void ln2mix_kernel(
    const u16* __restrict__ yb, const u16* __restrict__ o2b,
    const float2* __restrict__ st1,
    const float* __restrict__ g1, const float* __restrict__ be1,
    const float* __restrict__ g, const float* __restrict__ bt,
    const float* __restrict__ aw, const float* __restrict__ ab,
    float* __restrict__ st, u16* __restrict__ stb,
    float* __restrict__ hp, float* __restrict__ rem, float* __restrict__ uw,
    unsigned* __restrict__ tfact_next, unsigned* __restrict__ tfchg_next){
  int lane = threadIdx.x & 63;
  int row = blockIdx.x*4 + (threadIdx.x >> 6);
  float u = uw[row];
  if (u == 0.f) return;              // frozen at this step's entry: exact no-op (per-wave)
  size_t base = (size_t)row*512 + lane*8;
  float2 s1 = st1[row];
  float mu1 = s1.x, rstd1 = s1.y;
  int c0 = lane*8;
  float v[8], sv[8];
  {
    u16x8 y8 = *(const u16x8*)(yb + base);
    u16x8 o8 = *(const u16x8*)(o2b + base);
    const float4* sp = (const float4*)(st + base);
    float4 s0 = sp[0], s1f = sp[1];
    #pragma unroll
    for (int j=0;j<8;j++){
      float out1 = (b2f(y8[j]) - mu1)*rstd1*g1[c0+j] + be1[c0+j];
      v[j] = out1 + b2f(o8[j]);
    }
    sv[0]=s0.x; sv[1]=s0.y; sv[2]=s0.z; sv[3]=s0.w;
    sv[4]=s1f.x; sv[5]=s1f.y; sv[6]=s1f.z; sv[7]=s1f.w;
  }
  float sum=0.f, sq=0.f;
  #pragma unroll
  for (int j=0;j<8;j++){ sum += v[j]; sq += v[j]*v[j]; }
  sum = wred_sum(sum); sq = wred_sum(sq);
  float mean = sum*(1.f/512.f);
  float var  = sq*(1.f/512.f) - mean*mean;
  float rstd = rsqrtf(fmaxf(var, 0.f) + 1e-6f);
  float um1 = 1.f - u;
  float z[8]; u16x8 ob;
  #pragma unroll
  for (int j=0;j<8;j++){
    float y = (v[j]-mean)*rstd*g[c0+j] + bt[c0+j];
    z[j] = y*u + sv[j]*um1;
    ob[j] = f2b(z[j]);
  }
  float4* op = (float4*)(st + base);
  op[0] = make_float4(z[0],z[1],z[2],z[3]);
  op[1] = make_float4(z[4],z[5],z[6],z[7]);
  *(u16x8*)(stb + base) = ob;
  const float4* wp = (const float4*)aw + (size_t)lane*2;
  float4 w0 = wp[0], w1 = wp[1];
  float d = z[0]*w0.x + z[1]*w0.y + z[2]*w0.z + z[3]*w0.w
          + z[4]*w1.x + z[5]*w1.y + z[6]*w1.z + z[7]*w1.w;
  d = wred_sum(d);
  if (lane == 0){
    float t = d + ab[0];
    float p = 1.f / (1.f + expf(-t));
    float h = hp[row], r = rem[row];
    bool active_next = (h < 1.f);    // uw_{s+1} != 0 iff this (pre-update) h < 1
    float still = active_next ? 1.f : 0.f;
    float cand  = h + p*still;
    float nh  = (cand > 0.99f)  ? still : 0.f;
    float st2 = (cand <= 0.99f) ? still : 0.f;
    h += p*st2;
    r += nh*(1.f - h);
    h += nh*r;
    hp[row] = h; rem[row] = r;
    uw[row] = p*st2 + nh*r;
    // idempotent flag set: plain stores (no atomic contention; all writers store 1)
    tfchg_next[row >> 7] = 1u;
    if (active_next) tfact_next[row >> 7] = 1u;
  }
}

// ---------------- host launch ----------------
extern "C" void kernel_launch(void* const* d_in, const int* in_sizes, int n_in,
                              void* d_out, int out_size, void* d_ws, size_t ws_size,
                              hipStream_t stream){
  const float* x     = (const float*)d_in[0];
  const float* wq    = (const float*)d_in[1];
  const float* bq    = (const float*)d_in[2];
  const float* wk    = (const float*)d_in[3];
  const float* bk    = (const float*)d_in[4];
  const float* wv    = (const float*)d_in[5];
  const float* bv    = (const float*)d_in[6];
  const float* wo    = (const float*)d_in[7];
  const float* bo    = (const float*)d_in[8];
  const float* w1    = (const float*)d_in[9];
  const float* b1    = (const float*)d_in[10];
  const float* lnf_g = (const float*)d_in[11];
  const float* lnf_b = (const float*)d_in[12];
  const float* w2    = (const float*)d_in[13];
  const float* b2    = (const float*)d_in[14];
  const float* ln1_g = (const float*)d_in[15];
  const float* ln1_b = (const float*)d_in[16];
  const float* ln2_g = (const float*)d_in[17];
  const float* ln2_b = (const float*)d_in[18];
  const float* aw    = (const float*)d_in[19];
  const float* ab    = (const float*)d_in[20];
  float* st = (float*)d_out;

  char* cur = (char*)d_ws;
  auto alloc = [&](size_t n){ void* p = cur; cur += (n + 255) & ~(size_t)255; return p; };
  u16*  wqkv_t = (u16*)alloc((size_t)1536*512*2);
  u16*  wo_t   = (u16*)alloc((size_t)512*512*2);
  u16*  w1_t   = (u16*)alloc((size_t)2048*512*2);   // ln1_g-scaled
  u16*  w2_t   = (u16*)alloc((size_t)512*2048*2);   // lnf_g-scaled
  float* bqkv  = (float*)alloc(1536*4);
  float* G1    = (float*)alloc(2048*4);
  float* C1    = (float*)alloc(2048*4);
  float* G2    = (float*)alloc(512*4);
  float* C2    = (float*)alloc(512*4);
  float* pg    = (float*)alloc((size_t)16384*4);
  float* pc    = (float*)alloc((size_t)16384*4);
  u16*  stb    = (u16*)alloc((size_t)M_*512*2);
  u16*  qkv    = (u16*)alloc((size_t)M_*1536*2);
  u16*  vt     = (u16*)alloc((size_t)M_*512*2);     // persistent transposed V
  u16*  ctx    = (u16*)alloc((size_t)M_*512*2);
  u16*  yb     = (u16*)alloc((size_t)M_*512*2);
  u16*  o2b    = (u16*)alloc((size_t)M_*512*2);
  u16*  hbuf   = (u16*)alloc((size_t)M_*2048*2);
  float2* parts1 = (float2*)alloc((size_t)16*M_*8);
  float2* parts2 = (float2*)alloc((size_t)64*M_*8);
  float2* stats1 = (float2*)alloc((size_t)M_*8);
  float2* stats2 = (float2*)alloc((size_t)M_*8);
  float* halt  = (float*)alloc((size_t)3*M_*4);
  unsigned* flags = (unsigned*)alloc(256*4);        // act[2][64], chg[2][64]
  float* hp = halt, *rem = halt + M_, *uw = halt + 2*M_;

  prep_kernel<<<2048, 256, 0, stream>>>(x, aw, ab, st, stb, hp, rem, uw);
  packb_kernel<<<6, 256, 0, stream>>>(bq, bk, bv, bqkv, flags);
  tcast_kernel<<<64,  256, 0, stream>>>(wq, wqkv_t,            512, 512, nullptr);
  tcast_kernel<<<64,  256, 0, stream>>>(wk, wqkv_t + 512*512,  512, 512, nullptr);
  tcast_kernel<<<64,  256, 0, stream>>>(wv, wqkv_t + 1024*512, 512, 512, nullptr);
  tcast_kernel<<<64,  256, 0, stream>>>(wo, wo_t, 512, 512, nullptr);
  tcast_kernel<<<256, 256, 0, stream>>>(w1, w1_t, 512, 2048, ln1_g);
  tcast_kernel<<<256, 256, 0, stream>>>(w2, w2_t, 2048, 512, lnf_g);
  gcpart_kernel<<<dim3(8, 8),  256, 0, stream>>>(w1, ln1_g, ln1_b, pg, pc, 2048);
  gcred_kernel<<<8, 256, 0, stream>>>(pg, pc, G1, C1, 8, 2048);
  gcpart_kernel<<<dim3(32, 2), 256, 0, stream>>>(w2, lnf_g, lnf_b, pg, pc, 512);
  gcred_kernel<<<2, 256, 0, stream>>>(pg, pc, G2, C2, 32, 512);

  for (int s = 0; s < STEPS_; s++){
    unsigned* act_c = flags + (s & 1)*64;
    unsigned* act_n = flags + ((s+1) & 1)*64;
    unsigned* chg_c = flags + 128 + (s & 1)*64;
    unsigned* chg_n = flags + 128 + ((s+1) & 1)*64;
    gemm128_kernel<1><<<64*12, 512, 0, stream>>>(stb, wqkv_t, bqkv, qkv, 12, 512, 1536,
                                                 vt, nullptr, nullptr, nullptr, nullptr, nullptr,
                                                 chg_c, act_c);
    attn_kernel<<<512, 256, 0, stream>>>(qkv, vt, ctx, act_c);
    gemm128_kernel<3><<<64*4, 512, 0, stream>>>(ctx, wo_t, bo, yb, 4, 512, 512,
                                                nullptr, nullptr, nullptr, nullptr, parts1, stb,
                                                act_c, nullptr);
    stats_kernel<<<M_/256, 256, 0, stream>>>(parts1, stats1, 16, 1.f/512.f,
                                             act_c, nullptr, nullptr);
    gemm128_kernel<4><<<64*16, 512, 0, stream>>>(yb, w1_t, b1, hbuf, 16, 512, 2048,
                                                 nullptr, stats1, G1, C1, parts2, nullptr,
                                                 act_c, nullptr);
    stats_kernel<<<M_/256, 256, 0, stream>>>(parts2, stats2, 64, 1.f/2048.f,
                                             act_c, act_n, chg_n);
    gemm128_kernel<5><<<64*4, 512, 0, stream>>>(hbuf, w2_t, b2, o2b, 4, 2048, 512,
                                                nullptr, stats2, G2, C2, nullptr, nullptr,
                                                act_c, nullptr);
    ln2mix_kernel<<<M_/4, 256, 0, stream>>>(yb, o2b, stats1, ln1_g, ln1_b, ln2_g, ln2_b,
                                            aw, ab, st, stb, hp, rem, uw, act_n, chg_n);
  }
}

// Round 19
// 575.033 us; speedup vs baseline: 1.0289x; 1.0289x over previous
//
#include <hip/hip_runtime.h>
#include <cstdint>
#include <cstddef>

#define B_ 8
#define S_ 1024
#define D_ 512
#define H_ 8
#define DFF_ 2048
#define STEPS_ 6
#define M_ (B_*S_)   // 8192 tokens

typedef unsigned short u16;
typedef u16   u16x8 __attribute__((ext_vector_type(8)));
typedef short s16x8 __attribute__((ext_vector_type(8)));
typedef float f32x4 __attribute__((ext_vector_type(4)));
typedef float f32x16 __attribute__((ext_vector_type(16)));

__device__ __forceinline__ u16 f2b(float f){
  union { float f; unsigned u; } v; v.f = f;
  unsigned r = v.u + 0x7fffu + ((v.u >> 16) & 1u);
  return (u16)(r >> 16);
}
__device__ __forceinline__ float b2f(u16 u){
  union { unsigned u; float f; } v; v.u = ((unsigned)u) << 16;
  return v.f;
}
__device__ __forceinline__ unsigned cvtpk(float lo, float hi){
  unsigned r;
  asm("v_cvt_pk_bf16_f32 %0, %1, %2" : "=v"(r) : "v"(lo), "v"(hi));
  return r;
}
__device__ __forceinline__ void gload16(const void* g, void* l){
  __builtin_amdgcn_global_load_lds(
    (const __attribute__((address_space(1))) void*)g,
    (__attribute__((address_space(3))) void*)l, 16, 0, 0);
}
__device__ __forceinline__ float wred_sum(float v){
  #pragma unroll
  for (int m = 1; m < 64; m <<= 1) v += __shfl_xor(v, m, 64);
  return v;
}

// ---------------- prep: st = x, stb = bf16(x), initial halting state ----------------
__global__ __launch_bounds__(256) void prep_kernel(const float* __restrict__ x,
    const float* __restrict__ aw, const float* __restrict__ ab,
    float* __restrict__ st, u16* __restrict__ stb,
    float* __restrict__ hp, float* __restrict__ rem, float* __restrict__ uw){
  int tid = threadIdx.x; int l = tid & 63; int w = tid >> 6;
  size_t i = (size_t)blockIdx.x*256 + tid;     // one wave = one row
  const float4* xp = (const float4*)x + i*2;
  float4 a = xp[0], b = xp[1];
  ((float4*)st)[i*2]   = a;
  ((float4*)st)[i*2+1] = b;
  u16x8 o;
  o[0]=f2b(a.x); o[1]=f2b(a.y); o[2]=f2b(a.z); o[3]=f2b(a.w);
  o[4]=f2b(b.x); o[5]=f2b(b.y); o[6]=f2b(b.z); o[7]=f2b(b.w);
  ((u16x8*)stb)[i] = o;
  const float4* wp = (const float4*)aw + (size_t)l*2;
  float4 w0 = wp[0], w1 = wp[1];
  float d = a.x*w0.x + a.y*w0.y + a.z*w0.z + a.w*w0.w
          + b.x*w1.x + b.y*w1.y + b.z*w1.z + b.w*w1.w;
  d = wred_sum(d);
  if (l == 0){
    int row = blockIdx.x*4 + w;
    float t = d + ab[0];
    float p = 1.f / (1.f + expf(-t));
    // reference step with h=0, r=0
    float nh  = (p > 0.99f) ? 1.f : 0.f;
    float st2 = 1.f - nh;
    float h = p*st2;
    float r = nh*(1.f - h);
    h += nh*r;
    hp[row] = h; rem[row] = r;
    uw[row] = p*st2 + nh*r;
  }
}

// ---------------- tiled transpose-cast: W[K][N] f32 -> Wt[N][K] bf16, row-scaled ----------------
__global__ __launch_bounds__(256) void tcast_kernel(const float* __restrict__ W,
    u16* __restrict__ Wt, int K, int N, const float* __restrict__ scale){
  __shared__ u16 T[64*66];
  int tid = threadIdx.x;
  int nbt = N >> 6;
  int k0 = (blockIdx.x / nbt) << 6, n0 = (blockIdx.x % nbt) << 6;
  int r = tid >> 2, c4 = tid & 3;
  float sc = scale ? scale[k0 + r] : 1.f;
  const float* src = W + (size_t)(k0 + r)*N + n0 + c4*16;
  #pragma unroll
  for (int q = 0; q < 2; q++){
    float4 f0 = ((const float4*)src)[q*2], f1 = ((const float4*)src)[q*2+1];
    u16x8 t;
    t[0]=f2b(f0.x*sc); t[1]=f2b(f0.y*sc); t[2]=f2b(f0.z*sc); t[3]=f2b(f0.w*sc);
    t[4]=f2b(f1.x*sc); t[5]=f2b(f1.y*sc); t[6]=f2b(f1.z*sc); t[7]=f2b(f1.w*sc);
    *(u16x8*)&T[r*66 + c4*16 + q*8] = t;
  }
  __syncthreads();
  int n = tid >> 2;
  #pragma unroll
  for (int t2 = 0; t2 < 2; t2++){
    int sc2 = (tid & 3) + t2*4;
    u16x8 o;
    #pragma unroll
    for (int j = 0; j < 8; j++) o[j] = T[(sc2*8 + j)*66 + n];
    *(u16x8*)&Wt[(size_t)(n0 + n)*K + k0 + sc2*8] = o;
  }
}

// packb + per-step flag init: flags[step*128 + {0..63 act, 64..127 chg}], 7 slots
__global__ void packb_kernel(const float* __restrict__ bq, const float* __restrict__ bk,
                             const float* __restrict__ bv, float* __restrict__ bqkv,
                             unsigned* __restrict__ flags){
  int i = blockIdx.x*256 + threadIdx.x;
  if (i < 512)       bqkv[i] = bq[i];
  else if (i < 1024) bqkv[i] = bk[i-512];
  else if (i < 1536) bqkv[i] = bv[i-1024];
  if (i < 896) flags[i] = (i < 128) ? 1u : 0u;   // step 0 fully active/changed
}

// ---------------- G/C precompute (coalesced 2-stage) ----------------
__global__ __launch_bounds__(256) void gcpart_kernel(const float* __restrict__ W,
    const float* __restrict__ g, const float* __restrict__ be,
    float* __restrict__ pg, float* __restrict__ pc, int N){
  int kb = blockIdx.x, cb = blockIdx.y, t = threadIdx.x;
  __shared__ float gs[64], bs[64];
  if (t < 64){ gs[t] = g[kb*64 + t]; bs[t] = be[kb*64 + t]; }
  __syncthreads();
  int col = cb*256 + t;
  float ag = 0.f, ac = 0.f;
  #pragma unroll 8
  for (int k = 0; k < 64; k++){
    float w = W[(size_t)(kb*64 + k)*N + col];
    ag = fmaf(gs[k], w, ag);
    ac = fmaf(bs[k], w, ac);
  }
  pg[(size_t)kb*N + col] = ag;
  pc[(size_t)kb*N + col] = ac;
}

__global__ __launch_bounds__(256) void gcred_kernel(const float* __restrict__ pg,
    const float* __restrict__ pc, float* __restrict__ G, float* __restrict__ Cc,
    int np, int N){
  int col = blockIdx.x*256 + threadIdx.x;
  float sg = 0.f, sc = 0.f;
  for (int i = 0; i < np; i++){
    sg += pg[(size_t)i*N + col];
    sc += pc[(size_t)i*N + col];
  }
  G[col] = sg; Cc[col] = sc;
}

// ---------------- 128x128 GEMM, BK=64, 8 waves (512 thr), double-buffered ----------------
// EPI 1: qkv. Q-blocks (n0<512) gate on act[tm]; K/V blocks gate on chg[tm] && batch-active.
// EPI 3: wo:  y = acc + bias + resid(bf16 stb); bf16 out + row partials (np=16); skip by act
// EPI 4: ffn1: relu(LN-affine, stats from parts np=16); bf16 out + partials (np=64); skip by act
// EPI 5: ffn2: LN-affine (stats from parts np=64); bf16 out; skip by act
template<int EPI>
__global__ __launch_bounds__(512, 4) void gemm128_kernel(
    const u16* __restrict__ A, const u16* __restrict__ Bt,
    const float* __restrict__ bias, void* __restrict__ C,
    int ntn, int K, int ldo, u16* __restrict__ vt,
    const float2* __restrict__ pin, int np, float invD,
    const float* __restrict__ gvec,
    const float* __restrict__ cvec, float2* __restrict__ parts,
    const u16* __restrict__ resid16, const unsigned* __restrict__ tflag,
    const unsigned* __restrict__ actarr){
  __shared__ u16 Als[2][128*64];
  __shared__ u16 Bls[2][128*64];
  __shared__ float2 srow[128];
  int tid = threadIdx.x, l = tid & 63, w = tid >> 6;   // w in [0,8)
  int hi = l >> 4, ln = l & 15;
  int wm = w >> 2, wn = w & 3;                 // 2M x 4N wave grid; wave out 64x32
  int nwg = gridDim.x;
  int bid = blockIdx.x;
  int swz = (bid & 7) * (nwg >> 3) + (bid >> 3);   // XCD-contiguous (nwg % 8 == 0)
  int tn = swz % ntn, tm = swz / ntn;
  int m0 = tm << 7, n0 = tn << 7;
  if (EPI == 1){
    if (n0 < 512){                             // Q: only for active q-tiles
      if (!actarr[tm]) return;
    } else {                                   // K/V: fresh + batch has active queries
      int b8 = (tm >> 3) << 3;
      unsigned ba = actarr[b8]   | actarr[b8+1] | actarr[b8+2] | actarr[b8+3]
                  | actarr[b8+4] | actarr[b8+5] | actarr[b8+6] | actarr[b8+7];
      if (!ba || !tflag[tm]) return;
    }
  } else {
    if (!tflag[tm]) return;                    // freeze skip (uniform)
  }
  int rl8 = l >> 3;
  int cg = (l & 7) ^ rl8;                      // pre-swizzled 16B chunk
  size_t aoff = (size_t)(m0 + w*8 + rl8)*K + cg*8;
  size_t boff = (size_t)(n0 + w*8 + rl8)*K + cg*8;
  int nt = K >> 6;

  f32x4 acc[4][2];
  #pragma unroll
  for (int i=0;i<4;i++)
    #pragma unroll
    for (int j=0;j<2;j++) acc[i][j] = (f32x4){0.f,0.f,0.f,0.f};

  // per buffer per thread: 2 A-loads + 2 B-loads; wave-load covers 8 rows x 64 cols
  #define G128(buf, kt) do { \
    size_t kof = (size_t)(kt)*64; \
    _Pragma("unroll") \
    for (int j = 0; j < 2; j++){ \
      gload16(A  + aoff + (size_t)j*64*K + kof, &Als[buf][(j*8 + w)*512]); \
      gload16(Bt + boff + (size_t)j*64*K + kof, &Bls[buf][(j*8 + w)*512]); \
    } } while(0)

  G128(0, 0);
  if (EPI == 4 || EPI == 5){
    // per-row LN stats from partials (overlaps the first staging loads)
    for (int r = tid; r < 128; r += 512){
      float s = 0.f, q = 0.f;
      for (int p = 0; p < np; p++){
        float2 v = pin[(size_t)p*M_ + m0 + r];
        s += v.x; q += v.y;
      }
      float mu = s*invD;
      float var = q*invD - mu*mu;
      srow[r] = make_float2(mu, rsqrtf(fmaxf(var, 0.f) + 1e-6f));
    }
  }
  __syncthreads();

  for (int t = 0; t < nt; t++){
    int cur = t & 1;
    if (t+1 < nt) G128(cur^1, t+1);            // prefetch into the OTHER buffer
    s16x8 af[4][2], bf[2][2];
    #pragma unroll
    for (int mi=0;mi<4;mi++){
      int row = wm*64 + mi*16 + ln;
      #pragma unroll
      for (int kk=0;kk<2;kk++)
        af[mi][kk] = *(const s16x8*)&Als[cur][row*64 + (((kk*4+hi)^(row&7))*8)];
    }
    #pragma unroll
    for (int ni=0;ni<2;ni++){
      int row = wn*32 + ni*16 + ln;
      #pragma unroll
      for (int kk=0;kk<2;kk++)
        bf[ni][kk] = *(const s16x8*)&Bls[cur][row*64 + (((kk*4+hi)^(row&7))*8)];
    }
    #pragma unroll
    for (int mi=0;mi<4;mi++)
      #pragma unroll
      for (int ni=0;ni<2;ni++)
        #pragma unroll
        for (int kk=0;kk<2;kk++)
          acc[mi][ni] = __builtin_amdgcn_mfma_f32_16x16x32_bf16(af[mi][kk], bf[ni][kk], acc[mi][ni], 0,0,0);
    if (t+1 < nt) __syncthreads();
  }
  #undef G128

  if (EPI == 1){
    if (n0 >= 1024){
      #pragma unroll
      for (int mi=0;mi<4;mi++){
        int row0 = m0 + wm*64 + mi*16 + hi*4;
        int b = row0 >> 10, s0 = row0 & 1023;
        #pragma unroll
        for (int ni=0;ni<2;ni++){
          int vcol = (n0 - 1024) + wn*32 + ni*16 + ln;
          int h = vcol >> 6, d = vcol & 63;
          float bc = bias[1024 + vcol];
          uint2 pk;
          pk.x = cvtpk(acc[mi][ni][0] + bc, acc[mi][ni][1] + bc);
          pk.y = cvtpk(acc[mi][ni][2] + bc, acc[mi][ni][3] + bc);
          *(uint2*)&vt[((size_t)((b*8 + h)*64 + d))*1024 + s0] = pk;
        }
      }
      return;
    }
    float qs = (n0 < 512) ? 0.125f : 1.0f;     // fold softmax scale into Q
    #pragma unroll
    for (int mi=0;mi<4;mi++){
      int row0 = m0 + wm*64 + mi*16 + hi*4;
      #pragma unroll
      for (int ni=0;ni<2;ni++){
        int col = n0 + wn*32 + ni*16 + ln;
        float bc = bias[col];
        #pragma unroll
        for (int r=0;r<4;r++)
          ((u16*)C)[(size_t)(row0+r)*ldo + col] = f2b((acc[mi][ni][r] + bc)*qs);
      }
    }
    return;
  }

  if (EPI == 3){
    float bv[2];
    #pragma unroll
    for (int ni=0;ni<2;ni++) bv[ni] = bias[n0 + wn*32 + ni*16 + ln];
    #pragma unroll
    for (int mi=0;mi<4;mi++){
      int row0 = m0 + wm*64 + mi*16 + hi*4;
      #pragma unroll
      for (int r=0;r<4;r++){
        int row = row0 + r;
        float s = 0.f, q = 0.f;
        #pragma unroll
        for (int ni=0;ni<2;ni++){
          int col = n0 + wn*32 + ni*16 + ln;
          float v = acc[mi][ni][r] + bv[ni] + b2f(resid16[(size_t)row*ldo + col]);
          ((u16*)C)[(size_t)row*ldo + col] = f2b(v);
          s += v; q += v*v;
        }
        #pragma unroll
        for (int msk=1;msk<16;msk<<=1){ s += __shfl_xor(s,msk,64); q += __shfl_xor(q,msk,64); }
        if (ln == 0) parts[(size_t)(tn*4 + wn)*M_ + row] = make_float2(s, q);
      }
    }
    return;
  }

  // EPI 4 / 5
  {
    float gv[2], cv[2];
    #pragma unroll
    for (int ni=0;ni<2;ni++){
      int col = n0 + wn*32 + ni*16 + ln;
      gv[ni] = gvec[col];
      cv[ni] = cvec[col] + bias[col];
    }
    #pragma unroll
    for (int mi=0;mi<4;mi++){
      int lrow0 = wm*64 + mi*16 + hi*4;
      #pragma unroll
      for (int r=0;r<4;r++){
        int row = m0 + lrow0 + r;
        float2 sr = srow[lrow0 + r];
        float rmu = sr.y * sr.x;
        float s = 0.f, q = 0.f;
        #pragma unroll
        for (int ni=0;ni<2;ni++){
          int col = n0 + wn*32 + ni*16 + ln;
          float v = sr.y*acc[mi][ni][r] - rmu*gv[ni] + cv[ni];
          if (EPI == 4) v = fmaxf(v, 0.f);
          ((u16*)C)[(size_t)row*ldo + col] = f2b(v);
          s += v; q += v*v;
        }
        if (EPI == 4){
          #pragma unroll
          for (int msk=1;msk<16;msk<<=1){ s += __shfl_xor(s,msk,64); q += __shfl_xor(q,msk,64); }
          if (ln == 0) parts[(size_t)(tn*4 + wn)*M_ + row] = make_float2(s, q);
        }
      }
    }
  }
}

// ---------------- flash attention, 32x32 MFMA, swapped QK^T, permlane P-redistribute ----------------
__global__ __launch_bounds__(256) void attn_kernel(const u16* __restrict__ qkv,
                                                   const u16* __restrict__ vt,
                                                   u16* __restrict__ ctx,
                                                   const unsigned* __restrict__ tfact){
  __shared__ u16 Ks[2][64*64];
  __shared__ u16 Vs[2][64*64];
  int tid = threadIdx.x, l = tid & 63, w = tid >> 6;
  int q5 = l & 31, hi2 = l >> 5;
  int orig = ((blockIdx.x & 7) << 6) | (blockIdx.x >> 3);   // XCD-contiguous: one b per XCD
  int qt = orig & 7, h = (orig >> 3) & 7, b = orig >> 6;
  if (!tfact[b*8 + qt]) return;                             // freeze skip (uniform)
  size_t rowbase = (size_t)b * S_;

  int qrow = qt*128 + w*32 + q5;
  s16x8 bq[4];
  #pragma unroll
  for (int dk = 0; dk < 4; dk++)
    bq[dk] = *(const s16x8*)&qkv[(rowbase + qrow)*1536 + h*64 + dk*16 + hi2*8];

  int rl = l >> 3;
  int cg = (l & 7) ^ rl;
  const u16* kb = qkv + rowbase*1536 + 512 + h*64 + cg*8;
  const u16* vb = vt + (size_t)((b*8 + h)*64)*1024 + cg*8;

  f32x16 o[2];
  #pragma unroll
  for (int mt = 0; mt < 2; mt++)
    #pragma unroll
    for (int r = 0; r < 16; r++) o[mt][r] = 0.f;
  float l_ = 0.f;

  #define STAGE(buf, kt) do { \
    _Pragma("unroll") \
    for (int r2 = 0; r2 < 2; r2++){ \
      int rr = r2*32 + w*8; \
      gload16(kb + (size_t)((kt)*64 + rr + rl)*1536, &Ks[buf][rr*64]); \
      gload16(vb + (size_t)(rr + rl)*1024 + (kt)*64, &Vs[buf][rr*64]); \
    } } while(0)

  STAGE(0, 0);
  STAGE(1, 1);
  asm volatile("s_waitcnt vmcnt(4)" ::: "memory");
  __builtin_amdgcn_s_barrier();
  __builtin_amdgcn_sched_barrier(0);

  for (int kt = 0; kt < 16; kt++){
    int cur = kt & 1;
    s16x8 ak[2][4], av[2][4];
    #pragma unroll
    for (int mt = 0; mt < 2; mt++){
      int r0 = mt*32 + q5;
      int sw = r0 & 7;
      #pragma unroll
      for (int dk = 0; dk < 4; dk++)
        ak[mt][dk] = *(const s16x8*)&Ks[cur][r0*64 + (((2*dk + hi2) ^ sw)*8)];
      #pragma unroll
      for (int ks = 0; ks < 4; ks++)
        av[mt][ks] = *(const s16x8*)&Vs[cur][r0*64 + (((2*ks + hi2) ^ sw)*8)];
    }
    asm volatile("s_waitcnt lgkmcnt(0)" ::: "memory");
    __builtin_amdgcn_sched_barrier(0);
    __builtin_amdgcn_s_barrier();
    __builtin_amdgcn_sched_barrier(0);
    if (kt < 14) STAGE(cur, kt+2);

    f32x16 sacc[2];
    #pragma unroll
    for (int mt = 0; mt < 2; mt++){
      f32x16 acc;
      #pragma unroll
      for (int r = 0; r < 16; r++) acc[r] = 0.f;
      #pragma unroll
      for (int dk = 0; dk < 4; dk++)
        acc = __builtin_amdgcn_mfma_f32_32x32x16_bf16(ak[mt][dk], bq[dk], acc, 0,0,0);
      sacc[mt] = acc;
    }

    float p[2][16];
    float rs = 0.f;
    #pragma unroll
    for (int mt = 0; mt < 2; mt++)
      #pragma unroll
      for (int r = 0; r < 16; r++){
        float e = __expf(sacc[mt][r]);
        p[mt][r] = e; rs += e;
      }
    rs += __shfl_xor(rs, 32, 64);
    l_ += rs;

    unsigned wds[4][4];
    #pragma unroll
    for (int ks = 0; ks < 4; ks++){
      const int mt = ks >> 1, base = (ks & 1)*8;
      unsigned a0 = cvtpk(p[mt][base+0], p[mt][base+1]);
      unsigned b0 = cvtpk(p[mt][base+4], p[mt][base+5]);
      asm("v_permlane32_swap_b32 %0, %1" : "+v"(a0), "+v"(b0));
      unsigned a1 = cvtpk(p[mt][base+2], p[mt][base+3]);
      unsigned b1 = cvtpk(p[mt][base+6], p[mt][base+7]);
      asm("v_permlane32_swap_b32 %0, %1" : "+v"(a1), "+v"(b1));
      wds[ks][0] = a0; wds[ks][1] = a1; wds[ks][2] = b0; wds[ks][3] = b1;
    }

    #pragma unroll
    for (int ks = 0; ks < 4; ks++){
      union { unsigned u[4]; s16x8 v; } bp;
      bp.u[0] = wds[ks][0]; bp.u[1] = wds[ks][1];
      bp.u[2] = wds[ks][2]; bp.u[3] = wds[ks][3];
      #pragma unroll
      for (int mt = 0; mt < 2; mt++)
        o[mt] = __builtin_amdgcn_mfma_f32_32x32x16_bf16(av[mt][ks], bp.v, o[mt], 0,0,0);
    }

    if (kt < 15){
      if (kt < 14) asm volatile("s_waitcnt vmcnt(4)" ::: "memory");
      else         asm volatile("s_waitcnt vmcnt(0)" ::: "memory");
      __builtin_amdgcn_s_barrier();
      __builtin_amdgcn_sched_barrier(0);
    }
  }
  #undef STAGE

  __builtin_amdgcn_s_barrier();
  float inv = 1.f / l_;
  u16* ob = ((w < 2) ? (u16*)Ks : (u16*)Vs) + (w & 1)*2304;
  #pragma unroll
  for (int mt = 0; mt < 2; mt++)
    #pragma unroll
    for (int g = 0; g < 4; g++)
      #pragma unroll
      for (int p2 = 0; p2 < 2; p2++){
        unsigned wd = cvtpk(o[mt][g*4 + p2*2]*inv, o[mt][g*4 + p2*2 + 1]*inv);
        int d0 = mt*32 + g*8 + hi2*4 + p2*2;
        *(unsigned*)&ob[q5*72 + d0] = wd;
      }
  asm volatile("s_waitcnt lgkmcnt(0)" ::: "memory");
  __builtin_amdgcn_sched_barrier(0);
  int r2 = l >> 1, cb = (l & 1)*32;
  size_t row = rowbase + qt*128 + w*32 + r2;
  #pragma unroll
  for (int c = 0; c < 4; c++){
    uint4 v = *(uint4*)&ob[r2*72 + cb + c*8];
    *(uint4*)&ctx[row*512 + h*64 + cb + c*8] = v;
  }
}

// ---------------- LN2 + ACT mix + next-step halting update (4 rows / 256-thr block) ----------------
__global__ __launch_bounds__(256) void ln2mix_kernel(
    const u16* __restrict__ yb, const u16* __restrict__ o2b,
    const float2* __restrict__ parts1,
    const float* __restrict__ g1, const float* __restrict__ be1,
    const float* __restrict__ g, const float* __restrict__ bt,
    const float* __restrict__ aw, const float* __restrict__ ab,
    float* __restrict__ st, u16* __restrict__ stb,
    float* __restrict__ hp, float* __restrict__ rem, float* __restrict__ uw,
    unsigned* __restrict__ tfact_next, unsigned* __restrict__ tfchg_next){
  int lane = threadIdx.x & 63;
  int row = blockIdx.x*4 + (threadIdx.x >> 6);
  float u = uw[row];
  if (u == 0.f) return;              // frozen at this step's entry: exact no-op (per-wave)
  size_t base = (size_t)row*512 + lane*8;
  // row stats from wo partials (16 strips)
  float2 pp = parts1[(size_t)(lane & 15)*M_ + row];
  float ps = pp.x, pq = pp.y;
  #pragma unroll
  for (int msk=1;msk<16;msk<<=1){ ps += __shfl_xor(ps,msk,64); pq += __shfl_xor(pq,msk,64); }
  float mu1 = ps*(1.f/512.f);
  float var1 = pq*(1.f/512.f) - mu1*mu1;
  float rstd1 = rsqrtf(fmaxf(var1, 0.f) + 1e-6f);
  int c0 = lane*8;
  float v[8], sv[8];
  {
    u16x8 y8 = *(const u16x8*)(yb + base);
    u16x8 o8 = *(const u16x8*)(o2b + base);
    const float4* sp = (const float4*)(st + base);
    float4 s0 = sp[0], s1f = sp[1];
    #pragma unroll
    for (int j=0;j<8;j++){
      float out1 = (b2f(y8[j]) - mu1)*rstd1*g1[c0+j] + be1[c0+j];
      v[j] = out1 + b2f(o8[j]);
    }
    sv[0]=s0.x; sv[1]=s0.y; sv[2]=s0.z; sv[3]=s0.w;
    sv[4]=s1f.x; sv[5]=s1f.y; sv[6]=s1f.z; sv[7]=s1f.w;
  }
  float sum=0.f, sq=0.f;
  #pragma unroll
  for (int j=0;j<8;j++){ sum += v[j]; sq += v[j]*v[j]; }
  sum = wred_sum(sum); sq = wred_sum(sq);
  float mean = sum*(1.f/512.f);
  float var  = sq*(1.f/512.f) - mean*mean;
  float rstd = rsqrtf(fmaxf(var, 0.f) + 1e-6f);
  float um1 = 1.f - u;
  float z[8]; u16x8 ob;
  #pragma unroll
  for (int j=0;j<8;j++){
    float y = (v[j]-mean)*rstd*g[c0+j] + bt[c0+j];
    z[j] = y*u + sv[j]*um1;
    ob[j] = f2b(z[j]);
  }
  float4* op = (float4*)(st + base);
  op[0] = make_float4(z[0],z[1],z[2],z[3]);
  op[1] = make_float4(z[4],z[5],z[6],z[7]);
  *(u16x8*)(stb + base) = ob;
  const float4* wp = (const float4*)aw + (size_t)lane*2;
  float4 w0 = wp[0], w1 = wp[1];
  float d = z[0]*w0.x + z[1]*w0.y + z[2]*w0.z + z[3]*w0.w
          + z[4]*w1.x + z[5]*w1.y + z[6]*w1.z + z[7]*w1.w;
  d = wred_sum(d);
  if (lane == 0){
    float t = d + ab[0];
    float p = 1.f / (1.f + expf(-t));
    float h = hp[row], r = rem[row];
    bool active_next = (h < 1.f);    // uw_{s+1} != 0 iff this (pre-update) h < 1
    float still = active_next ? 1.f : 0.f;
    float cand  = h + p*still;
    float nh  = (cand > 0.99f)  ? still : 0.f;
    float st2 = (cand <= 0.99f) ? still : 0.f;
    h += p*st2;
    r += nh*(1.f - h);
    h += nh*r;
    hp[row] = h; rem[row] = r;
    uw[row] = p*st2 + nh*r;
    // idempotent flag set: plain stores (fresh per-step slot, zeroed once at init)
    tfchg_next[row >> 7] = 1u;
    if (active_next) tfact_next[row >> 7] = 1u;
  }
}

// ---------------- host launch ----------------
extern "C" void kernel_launch(void* const* d_in, const int* in_sizes, int n_in,
                              void* d_out, int out_size, void* d_ws, size_t ws_size,
                              hipStream_t stream){
  const float* x     = (const float*)d_in[0];
  const float* wq    = (const float*)d_in[1];
  const float* bq    = (const float*)d_in[2];
  const float* wk    = (const float*)d_in[3];
  const float* bk    = (const float*)d_in[4];
  const float* wv    = (const float*)d_in[5];
  const float* bv    = (const float*)d_in[6];
  const float* wo    = (const float*)d_in[7];
  const float* bo    = (const float*)d_in[8];
  const float* w1    = (const float*)d_in[9];
  const float* b1    = (const float*)d_in[10];
  const float* lnf_g = (const float*)d_in[11];
  const float* lnf_b = (const float*)d_in[12];
  const float* w2    = (const float*)d_in[13];
  const float* b2    = (const float*)d_in[14];
  const float* ln1_g = (const float*)d_in[15];
  const float* ln1_b = (const float*)d_in[16];
  const float* ln2_g = (const float*)d_in[17];
  const float* ln2_b = (const float*)d_in[18];
  const float* aw    = (const float*)d_in[19];
  const float* ab    = (const float*)d_in[20];
  float* st = (float*)d_out;

  char* cur = (char*)d_ws;
  auto alloc = [&](size_t n){ void* p = cur; cur += (n + 255) & ~(size_t)255; return p; };
  u16*  wqkv_t = (u16*)alloc((size_t)1536*512*2);
  u16*  wo_t   = (u16*)alloc((size_t)512*512*2);
  u16*  w1_t   = (u16*)alloc((size_t)2048*512*2);   // ln1_g-scaled
  u16*  w2_t   = (u16*)alloc((size_t)512*2048*2);   // lnf_g-scaled
  float* bqkv  = (float*)alloc(1536*4);
  float* G1    = (float*)alloc(2048*4);
  float* C1    = (float*)alloc(2048*4);
  float* G2    = (float*)alloc(512*4);
  float* C2    = (float*)alloc(512*4);
  float* pg    = (float*)alloc((size_t)16384*4);
  float* pc    = (float*)alloc((size_t)16384*4);
  u16*  stb    = (u16*)alloc((size_t)M_*512*2);
  u16*  qkv    = (u16*)alloc((size_t)M_*1536*2);
  u16*  vt     = (u16*)alloc((size_t)M_*512*2);     // persistent transposed V
  u16*  ctx    = (u16*)alloc((size_t)M_*512*2);
  u16*  yb     = (u16*)alloc((size_t)M_*512*2);
  u16*  o2b    = (u16*)alloc((size_t)M_*512*2);
  u16*  hbuf   = (u16*)alloc((size_t)M_*2048*2);
  float2* parts1 = (float2*)alloc((size_t)16*M_*8);
  float2* parts2 = (float2*)alloc((size_t)64*M_*8);
  float* halt  = (float*)alloc((size_t)3*M_*4);
  unsigned* flags = (unsigned*)alloc(896*4);        // 7 steps x {act[64], chg[64]}
  float* hp = halt, *rem = halt + M_, *uw = halt + 2*M_;

  prep_kernel<<<2048, 256, 0, stream>>>(x, aw, ab, st, stb, hp, rem, uw);
  packb_kernel<<<6, 256, 0, stream>>>(bq, bk, bv, bqkv, flags);
  tcast_kernel<<<64,  256, 0, stream>>>(wq, wqkv_t,            512, 512, nullptr);
  tcast_kernel<<<64,  256, 0, stream>>>(wk, wqkv_t + 512*512,  512, 512, nullptr);
  tcast_kernel<<<64,  256, 0, stream>>>(wv, wqkv_t + 1024*512, 512, 512, nullptr);
  tcast_kernel<<<64,  256, 0, stream>>>(wo, wo_t, 512, 512, nullptr);
  tcast_kernel<<<256, 256, 0, stream>>>(w1, w1_t, 512, 2048, ln1_g);
  tcast_kernel<<<256, 256, 0, stream>>>(w2, w2_t, 2048, 512, lnf_g);
  gcpart_kernel<<<dim3(8, 8),  256, 0, stream>>>(w1, ln1_g, ln1_b, pg, pc, 2048);
  gcred_kernel<<<8, 256, 0, stream>>>(pg, pc, G1, C1, 8, 2048);
  gcpart_kernel<<<dim3(32, 2), 256, 0, stream>>>(w2, lnf_g, lnf_b, pg, pc, 512);
  gcred_kernel<<<2, 256, 0, stream>>>(pg, pc, G2, C2, 32, 512);

  for (int s = 0; s < STEPS_; s++){
    unsigned* act_c = flags + s*128;
    unsigned* chg_c = act_c + 64;
    unsigned* act_n = flags + (s+1)*128;
    unsigned* chg_n = act_n + 64;
    gemm128_kernel<1><<<64*12, 512, 0, stream>>>(stb, wqkv_t, bqkv, qkv, 12, 512, 1536,
                                                 vt, nullptr, 0, 0.f, nullptr, nullptr, nullptr,
                                                 nullptr, chg_c, act_c);
    attn_kernel<<<512, 256, 0, stream>>>(qkv, vt, ctx, act_c);
    gemm128_kernel<3><<<64*4, 512, 0, stream>>>(ctx, wo_t, bo, yb, 4, 512, 512,
                                                nullptr, nullptr, 0, 0.f, nullptr, nullptr, parts1,
                                                stb, act_c, nullptr);
    gemm128_kernel<4><<<64*16, 512, 0, stream>>>(yb, w1_t, b1, hbuf, 16, 512, 2048,
                                                 nullptr, parts1, 16, 1.f/512.f, G1, C1, parts2,
                                                 nullptr, act_c, nullptr);
    gemm128_kernel<5><<<64*4, 512, 0, stream>>>(hbuf, w2_t, b2, o2b, 4, 2048, 512,
                                                nullptr, parts2, 64, 1.f/2048.f, G2, C2, nullptr,
                                                nullptr, act_c, nullptr);
    ln2mix_kernel<<<M_/4, 256, 0, stream>>>(yb, o2b, parts1, ln1_g, ln1_b, ln2_g, ln2_b,
                                            aw, ab, st, stb, hp, rem, uw, act_n, chg_n);
  }
}

// Round 20
// 543.249 us; speedup vs baseline: 1.0891x; 1.0585x over previous
//
#include <hip/hip_runtime.h>
#include <cstdint>
#include <cstddef>

#define B_ 8
#define S_ 1024
#define D_ 512
#define H_ 8
#define DFF_ 2048
#define STEPS_ 6
#define M_ (B_*S_)   // 8192 tokens

typedef unsigned short u16;
typedef u16   u16x8 __attribute__((ext_vector_type(8)));
typedef short s16x8 __attribute__((ext_vector_type(8)));
typedef float f32x4 __attribute__((ext_vector_type(4)));
typedef float f32x16 __attribute__((ext_vector_type(16)));

__device__ __forceinline__ u16 f2b(float f){
  union { float f; unsigned u; } v; v.f = f;
  unsigned r = v.u + 0x7fffu + ((v.u >> 16) & 1u);
  return (u16)(r >> 16);
}
__device__ __forceinline__ float b2f(u16 u){
  union { unsigned u; float f; } v; v.u = ((unsigned)u) << 16;
  return v.f;
}
__device__ __forceinline__ unsigned cvtpk(float lo, float hi){
  unsigned r;
  asm("v_cvt_pk_bf16_f32 %0, %1, %2" : "=v"(r) : "v"(lo), "v"(hi));
  return r;
}
__device__ __forceinline__ void gload16(const void* g, void* l){
  __builtin_amdgcn_global_load_lds(
    (const __attribute__((address_space(1))) void*)g,
    (__attribute__((address_space(3))) void*)l, 16, 0, 0);
}
__device__ __forceinline__ float wred_sum(float v){
  #pragma unroll
  for (int m = 1; m < 64; m <<= 1) v += __shfl_xor(v, m, 64);
  return v;
}

// ---------------- prep: st = x, stb = bf16(x), initial halting state ----------------
__global__ __launch_bounds__(256) void prep_kernel(const float* __restrict__ x,
    const float* __restrict__ aw, const float* __restrict__ ab,
    float* __restrict__ st, u16* __restrict__ stb,
    float* __restrict__ hp, float* __restrict__ rem, float* __restrict__ uw){
  int tid = threadIdx.x; int l = tid & 63; int w = tid >> 6;
  size_t i = (size_t)blockIdx.x*256 + tid;     // one wave = one row
  const float4* xp = (const float4*)x + i*2;
  float4 a = xp[0], b = xp[1];
  ((float4*)st)[i*2]   = a;
  ((float4*)st)[i*2+1] = b;
  u16x8 o;
  o[0]=f2b(a.x); o[1]=f2b(a.y); o[2]=f2b(a.z); o[3]=f2b(a.w);
  o[4]=f2b(b.x); o[5]=f2b(b.y); o[6]=f2b(b.z); o[7]=f2b(b.w);
  ((u16x8*)stb)[i] = o;
  const float4* wp = (const float4*)aw + (size_t)l*2;
  float4 w0 = wp[0], w1 = wp[1];
  float d = a.x*w0.x + a.y*w0.y + a.z*w0.z + a.w*w0.w
          + b.x*w1.x + b.y*w1.y + b.z*w1.z + b.w*w1.w;
  d = wred_sum(d);
  if (l == 0){
    int row = blockIdx.x*4 + w;
    float t = d + ab[0];
    float p = 1.f / (1.f + expf(-t));
    // reference step with h=0, r=0
    float nh  = (p > 0.99f) ? 1.f : 0.f;
    float st2 = 1.f - nh;
    float h = p*st2;
    float r = nh*(1.f - h);
    h += nh*r;
    hp[row] = h; rem[row] = r;
    uw[row] = p*st2 + nh*r;
  }
}

// ---------------- tiled transpose-cast: W[K][N] f32 -> Wt[N][K] bf16, row-scaled ----------------
__global__ __launch_bounds__(256) void tcast_kernel(const float* __restrict__ W,
    u16* __restrict__ Wt, int K, int N, const float* __restrict__ scale){
  __shared__ u16 T[64*66];
  int tid = threadIdx.x;
  int nbt = N >> 6;
  int k0 = (blockIdx.x / nbt) << 6, n0 = (blockIdx.x % nbt) << 6;
  int r = tid >> 2, c4 = tid & 3;
  float sc = scale ? scale[k0 + r] : 1.f;
  const float* src = W + (size_t)(k0 + r)*N + n0 + c4*16;
  #pragma unroll
  for (int q = 0; q < 2; q++){
    float4 f0 = ((const float4*)src)[q*2], f1 = ((const float4*)src)[q*2+1];
    u16x8 t;
    t[0]=f2b(f0.x*sc); t[1]=f2b(f0.y*sc); t[2]=f2b(f0.z*sc); t[3]=f2b(f0.w*sc);
    t[4]=f2b(f1.x*sc); t[5]=f2b(f1.y*sc); t[6]=f2b(f1.z*sc); t[7]=f2b(f1.w*sc);
    *(u16x8*)&T[r*66 + c4*16 + q*8] = t;
  }
  __syncthreads();
  int n = tid >> 2;
  #pragma unroll
  for (int t2 = 0; t2 < 2; t2++){
    int sc2 = (tid & 3) + t2*4;
    u16x8 o;
    #pragma unroll
    for (int j = 0; j < 8; j++) o[j] = T[(sc2*8 + j)*66 + n];
    *(u16x8*)&Wt[(size_t)(n0 + n)*K + k0 + sc2*8] = o;
  }
}

// packb + per-step flag init: flags[step*128 + {0..63 act, 64..127 chg}], 7 slots
__global__ void packb_kernel(const float* __restrict__ bq, const float* __restrict__ bk,
                             const float* __restrict__ bv, float* __restrict__ bqkv,
                             unsigned* __restrict__ flags){
  int i = blockIdx.x*256 + threadIdx.x;
  if (i < 512)       bqkv[i] = bq[i];
  else if (i < 1024) bqkv[i] = bk[i-512];
  else if (i < 1536) bqkv[i] = bv[i-1024];
  if (i < 896) flags[i] = (i < 128) ? 1u : 0u;   // step 0 fully active/changed
}

// ---------------- G/C precompute (coalesced 2-stage) ----------------
__global__ __launch_bounds__(256) void gcpart_kernel(const float* __restrict__ W,
    const float* __restrict__ g, const float* __restrict__ be,
    float* __restrict__ pg, float* __restrict__ pc, int N){
  int kb = blockIdx.x, cb = blockIdx.y, t = threadIdx.x;
  __shared__ float gs[64], bs[64];
  if (t < 64){ gs[t] = g[kb*64 + t]; bs[t] = be[kb*64 + t]; }
  __syncthreads();
  int col = cb*256 + t;
  float ag = 0.f, ac = 0.f;
  #pragma unroll 8
  for (int k = 0; k < 64; k++){
    float w = W[(size_t)(kb*64 + k)*N + col];
    ag = fmaf(gs[k], w, ag);
    ac = fmaf(bs[k], w, ac);
  }
  pg[(size_t)kb*N + col] = ag;
  pc[(size_t)kb*N + col] = ac;
}

__global__ __launch_bounds__(256) void gcred_kernel(const float* __restrict__ pg,
    const float* __restrict__ pc, float* __restrict__ G, float* __restrict__ Cc,
    int np, int N){
  int col = blockIdx.x*256 + threadIdx.x;
  float sg = 0.f, sc = 0.f;
  for (int i = 0; i < np; i++){
    sg += pg[(size_t)i*N + col];
    sc += pc[(size_t)i*N + col];
  }
  G[col] = sg; Cc[col] = sc;
}

// ---------------- 128x128 GEMM, BK=64, 8 waves (512 thr), double-buffered ----------------
// parts layout: row-major parts[row][strip] (16 strips for wo, 64 for ffn1)
// EPI 1: qkv. Q-blocks (n0<512) gate on act[tm]; K/V blocks gate on chg[tm] && batch-active.
// EPI 3: wo:  y = acc + bias + resid(bf16 stb); bf16 out + parts[row][16]; skip by act
// EPI 4: ffn1: relu(LN-affine, stats from pin np=16); bf16 out + parts[row][64]; skip by act
// EPI 5: ffn2: LN-affine (stats from pin np=64); bf16 out; skip by act
template<int EPI>
__global__ __launch_bounds__(512, 4) void gemm128_kernel(
    const u16* __restrict__ A, const u16* __restrict__ Bt,
    const float* __restrict__ bias, void* __restrict__ C,
    int ntn, int K, int ldo, u16* __restrict__ vt,
    const float2* __restrict__ pin, int np, float invD,
    const float* __restrict__ gvec,
    const float* __restrict__ cvec, float2* __restrict__ parts,
    const u16* __restrict__ resid16, const unsigned* __restrict__ tflag,
    const unsigned* __restrict__ actarr){
  __shared__ u16 Als[2][128*64];
  __shared__ u16 Bls[2][128*64];
  __shared__ float2 srow[128];
  int tid = threadIdx.x, l = tid & 63, w = tid >> 6;   // w in [0,8)
  int hi = l >> 4, ln = l & 15;
  int wm = w >> 2, wn = w & 3;                 // 2M x 4N wave grid; wave out 64x32
  int nwg = gridDim.x;
  int bid = blockIdx.x;
  int swz = (bid & 7) * (nwg >> 3) + (bid >> 3);   // XCD-contiguous (nwg % 8 == 0)
  int tn = swz % ntn, tm = swz / ntn;
  int m0 = tm << 7, n0 = tn << 7;
  if (EPI == 1){
    if (n0 < 512){                             // Q: only for active q-tiles
      if (!actarr[tm]) return;
    } else {                                   // K/V: fresh + batch has active queries
      int b8 = (tm >> 3) << 3;
      unsigned ba = actarr[b8]   | actarr[b8+1] | actarr[b8+2] | actarr[b8+3]
                  | actarr[b8+4] | actarr[b8+5] | actarr[b8+6] | actarr[b8+7];
      if (!ba || !tflag[tm]) return;
    }
  } else {
    if (!tflag[tm]) return;                    // freeze skip (uniform)
  }
  int rl8 = l >> 3;
  int cg = (l & 7) ^ rl8;                      // pre-swizzled 16B chunk
  size_t aoff = (size_t)(m0 + w*8 + rl8)*K + cg*8;
  size_t boff = (size_t)(n0 + w*8 + rl8)*K + cg*8;
  int nt = K >> 6;

  f32x4 acc[4][2];
  #pragma unroll
  for (int i=0;i<4;i++)
    #pragma unroll
    for (int j=0;j<2;j++) acc[i][j] = (f32x4){0.f,0.f,0.f,0.f};

  // per buffer per thread: 2 A-loads + 2 B-loads; wave-load covers 8 rows x 64 cols
  #define G128(buf, kt) do { \
    size_t kof = (size_t)(kt)*64; \
    _Pragma("unroll") \
    for (int j = 0; j < 2; j++){ \
      gload16(A  + aoff + (size_t)j*64*K + kof, &Als[buf][(j*8 + w)*512]); \
      gload16(Bt + boff + (size_t)j*64*K + kof, &Bls[buf][(j*8 + w)*512]); \
    } } while(0)

  G128(0, 0);
  if (EPI == 4 || EPI == 5){
    // per-row LN stats from row-major partials (contiguous per row)
    for (int r = tid; r < 128; r += 512){
      const float2* pr = pin + (size_t)(m0 + r)*np;
      float s = 0.f, q = 0.f;
      for (int p = 0; p < np; p++){
        float2 v = pr[p];
        s += v.x; q += v.y;
      }
      float mu = s*invD;
      float var = q*invD - mu*mu;
      srow[r] = make_float2(mu, rsqrtf(fmaxf(var, 0.f) + 1e-6f));
    }
  }
  __syncthreads();

  for (int t = 0; t < nt; t++){
    int cur = t & 1;
    if (t+1 < nt) G128(cur^1, t+1);            // prefetch into the OTHER buffer
    s16x8 af[4][2], bf[2][2];
    #pragma unroll
    for (int mi=0;mi<4;mi++){
      int row = wm*64 + mi*16 + ln;
      #pragma unroll
      for (int kk=0;kk<2;kk++)
        af[mi][kk] = *(const s16x8*)&Als[cur][row*64 + (((kk*4+hi)^(row&7))*8)];
    }
    #pragma unroll
    for (int ni=0;ni<2;ni++){
      int row = wn*32 + ni*16 + ln;
      #pragma unroll
      for (int kk=0;kk<2;kk++)
        bf[ni][kk] = *(const s16x8*)&Bls[cur][row*64 + (((kk*4+hi)^(row&7))*8)];
    }
    #pragma unroll
    for (int mi=0;mi<4;mi++)
      #pragma unroll
      for (int ni=0;ni<2;ni++)
        #pragma unroll
        for (int kk=0;kk<2;kk++)
          acc[mi][ni] = __builtin_amdgcn_mfma_f32_16x16x32_bf16(af[mi][kk], bf[ni][kk], acc[mi][ni], 0,0,0);
    if (t+1 < nt) __syncthreads();
  }
  #undef G128

  if (EPI == 1){
    if (n0 >= 1024){
      #pragma unroll
      for (int mi=0;mi<4;mi++){
        int row0 = m0 + wm*64 + mi*16 + hi*4;
        int b = row0 >> 10, s0 = row0 & 1023;
        #pragma unroll
        for (int ni=0;ni<2;ni++){
          int vcol = (n0 - 1024) + wn*32 + ni*16 + ln;
          int h = vcol >> 6, d = vcol & 63;
          float bc = bias[1024 + vcol];
          uint2 pk;
          pk.x = cvtpk(acc[mi][ni][0] + bc, acc[mi][ni][1] + bc);
          pk.y = cvtpk(acc[mi][ni][2] + bc, acc[mi][ni][3] + bc);
          *(uint2*)&vt[((size_t)((b*8 + h)*64 + d))*1024 + s0] = pk;
        }
      }
      return;
    }
    float qs = (n0 < 512) ? 0.125f : 1.0f;     // fold softmax scale into Q
    #pragma unroll
    for (int mi=0;mi<4;mi++){
      int row0 = m0 + wm*64 + mi*16 + hi*4;
      #pragma unroll
      for (int ni=0;ni<2;ni++){
        int col = n0 + wn*32 + ni*16 + ln;
        float bc = bias[col];
        #pragma unroll
        for (int r=0;r<4;r++)
          ((u16*)C)[(size_t)(row0+r)*ldo + col] = f2b((acc[mi][ni][r] + bc)*qs);
      }
    }
    return;
  }

  if (EPI == 3){
    float bv[2];
    #pragma unroll
    for (int ni=0;ni<2;ni++) bv[ni] = bias[n0 + wn*32 + ni*16 + ln];
    #pragma unroll
    for (int mi=0;mi<4;mi++){
      int row0 = m0 + wm*64 + mi*16 + hi*4;
      #pragma unroll
      for (int r=0;r<4;r++){
        int row = row0 + r;
        float s = 0.f, q = 0.f;
        #pragma unroll
        for (int ni=0;ni<2;ni++){
          int col = n0 + wn*32 + ni*16 + ln;
          float v = acc[mi][ni][r] + bv[ni] + b2f(resid16[(size_t)row*ldo + col]);
          ((u16*)C)[(size_t)row*ldo + col] = f2b(v);
          s += v; q += v*v;
        }
        #pragma unroll
        for (int msk=1;msk<16;msk<<=1){ s += __shfl_xor(s,msk,64); q += __shfl_xor(q,msk,64); }
        if (ln == 0) parts[(size_t)row*16 + (tn*4 + wn)] = make_float2(s, q);
      }
    }
    return;
  }

  // EPI 4 / 5
  {
    float gv[2], cv[2];
    #pragma unroll
    for (int ni=0;ni<2;ni++){
      int col = n0 + wn*32 + ni*16 + ln;
      gv[ni] = gvec[col];
      cv[ni] = cvec[col] + bias[col];
    }
    #pragma unroll
    for (int mi=0;mi<4;mi++){
      int lrow0 = wm*64 + mi*16 + hi*4;
      #pragma unroll
      for (int r=0;r<4;r++){
        int row = m0 + lrow0 + r;
        float2 sr = srow[lrow0 + r];
        float rmu = sr.y * sr.x;
        float s = 0.f, q = 0.f;
        #pragma unroll
        for (int ni=0;ni<2;ni++){
          int col = n0 + wn*32 + ni*16 + ln;
          float v = sr.y*acc[mi][ni][r] - rmu*gv[ni] + cv[ni];
          if (EPI == 4) v = fmaxf(v, 0.f);
          ((u16*)C)[(size_t)row*ldo + col] = f2b(v);
          s += v; q += v*v;
        }
        if (EPI == 4){
          #pragma unroll
          for (int msk=1;msk<16;msk<<=1){ s += __shfl_xor(s,msk,64); q += __shfl_xor(q,msk,64); }
          if (ln == 0) parts[(size_t)row*64 + (tn*4 + wn)] = make_float2(s, q);
        }
      }
    }
  }
}

// ---------------- flash attention, 32x32 MFMA, swapped QK^T, permlane P-redistribute ----------------
__global__ __launch_bounds__(256) void attn_kernel(const u16* __restrict__ qkv,
                                                   const u16* __restrict__ vt,
                                                   u16* __restrict__ ctx,
                                                   const unsigned* __restrict__ tfact){
  __shared__ u16 Ks[2][64*64];
  __shared__ u16 Vs[2][64*64];
  int tid = threadIdx.x, l = tid & 63, w = tid >> 6;
  int q5 = l & 31, hi2 = l >> 5;
  int orig = ((blockIdx.x & 7) << 6) | (blockIdx.x >> 3);   // XCD-contiguous: one b per XCD
  int qt = orig & 7, h = (orig >> 3) & 7, b = orig >> 6;
  if (!tfact[b*8 + qt]) return;                             // freeze skip (uniform)
  size_t rowbase = (size_t)b * S_;

  int qrow = qt*128 + w*32 + q5;
  s16x8 bq[4];
  #pragma unroll
  for (int dk = 0; dk < 4; dk++)
    bq[dk] = *(const s16x8*)&qkv[(rowbase + qrow)*1536 + h*64 + dk*16 + hi2*8];

  int rl = l >> 3;
  int cg = (l & 7) ^ rl;
  const u16* kb = qkv + rowbase*1536 + 512 + h*64 + cg*8;
  const u16* vb = vt + (size_t)((b*8 + h)*64)*1024 + cg*8;

  f32x16 o[2];
  #pragma unroll
  for (int mt = 0; mt < 2; mt++)
    #pragma unroll
    for (int r = 0; r < 16; r++) o[mt][r] = 0.f;
  float l_ = 0.f;

  #define STAGE(buf, kt) do { \
    _Pragma("unroll") \
    for (int r2 = 0; r2 < 2; r2++){ \
      int rr = r2*32 + w*8; \
      gload16(kb + (size_t)((kt)*64 + rr + rl)*1536, &Ks[buf][rr*64]); \
      gload16(vb + (size_t)(rr + rl)*1024 + (kt)*64, &Vs[buf][rr*64]); \
    } } while(0)

  STAGE(0, 0);
  STAGE(1, 1);
  asm volatile("s_waitcnt vmcnt(4)" ::: "memory");
  __builtin_amdgcn_s_barrier();
  __builtin_amdgcn_sched_barrier(0);

  for (int kt = 0; kt < 16; kt++){
    int cur = kt & 1;
    s16x8 ak[2][4], av[2][4];
    #pragma unroll
    for (int mt = 0; mt < 2; mt++){
      int r0 = mt*32 + q5;
      int sw = r0 & 7;
      #pragma unroll
      for (int dk = 0; dk < 4; dk++)
        ak[mt][dk] = *(const s16x8*)&Ks[cur][r0*64 + (((2*dk + hi2) ^ sw)*8)];
      #pragma unroll
      for (int ks = 0; ks < 4; ks++)
        av[mt][ks] = *(const s16x8*)&Vs[cur][r0*64 + (((2*ks + hi2) ^ sw)*8)];
    }
    asm volatile("s_waitcnt lgkmcnt(0)" ::: "memory");
    __builtin_amdgcn_sched_barrier(0);
    __builtin_amdgcn_s_barrier();
    __builtin_amdgcn_sched_barrier(0);
    if (kt < 14) STAGE(cur, kt+2);

    f32x16 sacc[2];
    #pragma unroll
    for (int mt = 0; mt < 2; mt++){
      f32x16 acc;
      #pragma unroll
      for (int r = 0; r < 16; r++) acc[r] = 0.f;
      #pragma unroll
      for (int dk = 0; dk < 4; dk++)
        acc = __builtin_amdgcn_mfma_f32_32x32x16_bf16(ak[mt][dk], bq[dk], acc, 0,0,0);
      sacc[mt] = acc;
    }

    float p[2][16];
    float rs = 0.f;
    #pragma unroll
    for (int mt = 0; mt < 2; mt++)
      #pragma unroll
      for (int r = 0; r < 16; r++){
        float e = __expf(sacc[mt][r]);
        p[mt][r] = e; rs += e;
      }
    rs += __shfl_xor(rs, 32, 64);
    l_ += rs;

    unsigned wds[4][4];
    #pragma unroll
    for (int ks = 0; ks < 4; ks++){
      const int mt = ks >> 1, base = (ks & 1)*8;
      unsigned a0 = cvtpk(p[mt][base+0], p[mt][base+1]);
      unsigned b0 = cvtpk(p[mt][base+4], p[mt][base+5]);
      asm("v_permlane32_swap_b32 %0, %1" : "+v"(a0), "+v"(b0));
      unsigned a1 = cvtpk(p[mt][base+2], p[mt][base+3]);
      unsigned b1 = cvtpk(p[mt][base+6], p[mt][base+7]);
      asm("v_permlane32_swap_b32 %0, %1" : "+v"(a1), "+v"(b1));
      wds[ks][0] = a0; wds[ks][1] = a1; wds[ks][2] = b0; wds[ks][3] = b1;
    }

    #pragma unroll
    for (int ks = 0; ks < 4; ks++){
      union { unsigned u[4]; s16x8 v; } bp;
      bp.u[0] = wds[ks][0]; bp.u[1] = wds[ks][1];
      bp.u[2] = wds[ks][2]; bp.u[3] = wds[ks][3];
      #pragma unroll
      for (int mt = 0; mt < 2; mt++)
        o[mt] = __builtin_amdgcn_mfma_f32_32x32x16_bf16(av[mt][ks], bp.v, o[mt], 0,0,0);
    }

    if (kt < 15){
      if (kt < 14) asm volatile("s_waitcnt vmcnt(4)" ::: "memory");
      else         asm volatile("s_waitcnt vmcnt(0)" ::: "memory");
      __builtin_amdgcn_s_barrier();
      __builtin_amdgcn_sched_barrier(0);
    }
  }
  #undef STAGE

  __builtin_amdgcn_s_barrier();
  float inv = 1.f / l_;
  u16* ob = ((w < 2) ? (u16*)Ks : (u16*)Vs) + (w & 1)*2304;
  #pragma unroll
  for (int mt = 0; mt < 2; mt++)
    #pragma unroll
    for (int g = 0; g < 4; g++)
      #pragma unroll
      for (int p2 = 0; p2 < 2; p2++){
        unsigned wd = cvtpk(o[mt][g*4 + p2*2]*inv, o[mt][g*4 + p2*2 + 1]*inv);
        int d0 = mt*32 + g*8 + hi2*4 + p2*2;
        *(unsigned*)&ob[q5*72 + d0] = wd;
      }
  asm volatile("s_waitcnt lgkmcnt(0)" ::: "memory");
  __builtin_amdgcn_sched_barrier(0);
  int r2 = l >> 1, cb = (l & 1)*32;
  size_t row = rowbase + qt*128 + w*32 + r2;
  #pragma unroll
  for (int c = 0; c < 4; c++){
    uint4 v = *(uint4*)&ob[r2*72 + cb + c*8];
    *(uint4*)&ctx[row*512 + h*64 + cb + c*8] = v;
  }
}

// ---------------- LN2 + ACT mix + next-step halting update (4 rows / 256-thr block) ----------------
__global__ __launch_bounds__(256) void ln2mix_kernel(
    const u16* __restrict__ yb, const u16* __restrict__ o2b,
    const float2* __restrict__ parts1,
    const float* __restrict__ g1, const float* __restrict__ be1,
    const float* __restrict__ g, const float* __restrict__ bt,
    const float* __restrict__ aw, const float* __restrict__ ab,
    float* __restrict__ st, u16* __restrict__ stb,
    float* __restrict__ hp, float* __restrict__ rem, float* __restrict__ uw,
    unsigned* __restrict__ tfact_next, unsigned* __restrict__ tfchg_next){
  int lane = threadIdx.x & 63;
  int row = blockIdx.x*4 + (threadIdx.x >> 6);
  float u = uw[row];
  if (u == 0.f) return;              // frozen at this step's entry: exact no-op (per-wave)
  size_t base = (size_t)row*512 + lane*8;
  // row stats from wo partials (16 consecutive strips of this row)
  float2 pp = parts1[(size_t)row*16 + (lane & 15)];
  float ps = pp.x, pq = pp.y;
  #pragma unroll
  for (int msk=1;msk<16;msk<<=1){ ps += __shfl_xor(ps,msk,64); pq += __shfl_xor(pq,msk,64); }
  float mu1 = ps*(1.f/512.f);
  float var1 = pq*(1.f/512.f) - mu1*mu1;
  float rstd1 = rsqrtf(fmaxf(var1, 0.f) + 1e-6f);
  int c0 = lane*8;
  float v[8], sv[8];
  {
    u16x8 y8 = *(const u16x8*)(yb + base);
    u16x8 o8 = *(const u16x8*)(o2b + base);
    const float4* sp = (const float4*)(st + base);
    float4 s0 = sp[0], s1f = sp[1];
    #pragma unroll
    for (int j=0;j<8;j++){
      float out1 = (b2f(y8[j]) - mu1)*rstd1*g1[c0+j] + be1[c0+j];
      v[j] = out1 + b2f(o8[j]);
    }
    sv[0]=s0.x; sv[1]=s0.y; sv[2]=s0.z; sv[3]=s0.w;
    sv[4]=s1f.x; sv[5]=s1f.y; sv[6]=s1f.z; sv[7]=s1f.w;
  }
  float sum=0.f, sq=0.f;
  #pragma unroll
  for (int j=0;j<8;j++){ sum += v[j]; sq += v[j]*v[j]; }
  sum = wred_sum(sum); sq = wred_sum(sq);
  float mean = sum*(1.f/512.f);
  float var  = sq*(1.f/512.f) - mean*mean;
  float rstd = rsqrtf(fmaxf(var, 0.f) + 1e-6f);
  float um1 = 1.f - u;
  float z[8]; u16x8 ob;
  #pragma unroll
  for (int j=0;j<8;j++){
    float y = (v[j]-mean)*rstd*g[c0+j] + bt[c0+j];
    z[j] = y*u + sv[j]*um1;
    ob[j] = f2b(z[j]);
  }
  float4* op = (float4*)(st + base);
  op[0] = make_float4(z[0],z[1],z[2],z[3]);
  op[1] = make_float4(z[4],z[5],z[6],z[7]);
  *(u16x8*)(stb + base) = ob;
  const float4* wp = (const float4*)aw + (size_t)lane*2;
  float4 w0 = wp[0], w1 = wp[1];
  float d = z[0]*w0.x + z[1]*w0.y + z[2]*w0.z + z[3]*w0.w
          + z[4]*w1.x + z[5]*w1.y + z[6]*w1.z + z[7]*w1.w;
  d = wred_sum(d);
  if (lane == 0){
    float t = d + ab[0];
    float p = 1.f / (1.f + expf(-t));
    float h = hp[row], r = rem[row];
    bool active_next = (h < 1.f);    // uw_{s+1} != 0 iff this (pre-update) h < 1
    float still = active_next ? 1.f : 0.f;
    float cand  = h + p*still;
    float nh  = (cand > 0.99f)  ? still : 0.f;
    float st2 = (cand <= 0.99f) ? still : 0.f;
    h += p*st2;
    r += nh*(1.f - h);
    h += nh*r;
    hp[row] = h; rem[row] = r;
    uw[row] = p*st2 + nh*r;
    // idempotent flag set: plain stores (fresh per-step slot, zeroed once at init)
    tfchg_next[row >> 7] = 1u;
    if (active_next) tfact_next[row >> 7] = 1u;
  }
}

// ---------------- host launch ----------------
extern "C" void kernel_launch(void* const* d_in, const int* in_sizes, int n_in,
                              void* d_out, int out_size, void* d_ws, size_t ws_size,
                              hipStream_t stream){
  const float* x     = (const float*)d_in[0];
  const float* wq    = (const float*)d_in[1];
  const float* bq    = (const float*)d_in[2];
  const float* wk    = (const float*)d_in[3];
  const float* bk    = (const float*)d_in[4];
  const float* wv    = (const float*)d_in[5];
  const float* bv    = (const float*)d_in[6];
  const float* wo    = (const float*)d_in[7];
  const float* bo    = (const float*)d_in[8];
  const float* w1    = (const float*)d_in[9];
  const float* b1    = (const float*)d_in[10];
  const float* lnf_g = (const float*)d_in[11];
  const float* lnf_b = (const float*)d_in[12];
  const float* w2    = (const float*)d_in[13];
  const float* b2    = (const float*)d_in[14];
  const float* ln1_g = (const float*)d_in[15];
  const float* ln1_b = (const float*)d_in[16];
  const float* ln2_g = (const float*)d_in[17];
  const float* ln2_b = (const float*)d_in[18];
  const float* aw    = (const float*)d_in[19];
  const float* ab    = (const float*)d_in[20];
  float* st = (float*)d_out;

  char* cur = (char*)d_ws;
  auto alloc = [&](size_t n){ void* p = cur; cur += (n + 255) & ~(size_t)255; return p; };
  u16*  wqkv_t = (u16*)alloc((size_t)1536*512*2);
  u16*  wo_t   = (u16*)alloc((size_t)512*512*2);
  u16*  w1_t   = (u16*)alloc((size_t)2048*512*2);   // ln1_g-scaled
  u16*  w2_t   = (u16*)alloc((size_t)512*2048*2);   // lnf_g-scaled
  float* bqkv  = (float*)alloc(1536*4);
  float* G1    = (float*)alloc(2048*4);
  float* C1    = (float*)alloc(2048*4);
  float* G2    = (float*)alloc(512*4);
  float* C2    = (float*)alloc(512*4);
  float* pg    = (float*)alloc((size_t)16384*4);
  float* pc    = (float*)alloc((size_t)16384*4);
  u16*  stb    = (u16*)alloc((size_t)M_*512*2);
  u16*  qkv    = (u16*)alloc((size_t)M_*1536*2);
  u16*  vt     = (u16*)alloc((size_t)M_*512*2);     // persistent transposed V
  u16*  ctx    = (u16*)alloc((size_t)M_*512*2);
  u16*  yb     = (u16*)alloc((size_t)M_*512*2);
  u16*  o2b    = (u16*)alloc((size_t)M_*512*2);
  u16*  hbuf   = (u16*)alloc((size_t)M_*2048*2);
  float2* parts1 = (float2*)alloc((size_t)M_*16*8);   // [row][16]
  float2* parts2 = (float2*)alloc((size_t)M_*64*8);   // [row][64]
  float* halt  = (float*)alloc((size_t)3*M_*4);
  unsigned* flags = (unsigned*)alloc(896*4);        // 7 steps x {act[64], chg[64]}
  float* hp = halt, *rem = halt + M_, *uw = halt + 2*M_;

  prep_kernel<<<2048, 256, 0, stream>>>(x, aw, ab, st, stb, hp, rem, uw);
  packb_kernel<<<6, 256, 0, stream>>>(bq, bk, bv, bqkv, flags);
  tcast_kernel<<<64,  256, 0, stream>>>(wq, wqkv_t,            512, 512, nullptr);
  tcast_kernel<<<64,  256, 0, stream>>>(wk, wqkv_t + 512*512,  512, 512, nullptr);
  tcast_kernel<<<64,  256, 0, stream>>>(wv, wqkv_t + 1024*512, 512, 512, nullptr);
  tcast_kernel<<<64,  256, 0, stream>>>(wo, wo_t, 512, 512, nullptr);
  tcast_kernel<<<256, 256, 0, stream>>>(w1, w1_t, 512, 2048, ln1_g);
  tcast_kernel<<<256, 256, 0, stream>>>(w2, w2_t, 2048, 512, lnf_g);
  gcpart_kernel<<<dim3(8, 8),  256, 0, stream>>>(w1, ln1_g, ln1_b, pg, pc, 2048);
  gcred_kernel<<<8, 256, 0, stream>>>(pg, pc, G1, C1, 8, 2048);
  gcpart_kernel<<<dim3(32, 2), 256, 0, stream>>>(w2, lnf_g, lnf_b, pg, pc, 512);
  gcred_kernel<<<2, 256, 0, stream>>>(pg, pc, G2, C2, 32, 512);

  for (int s = 0; s < STEPS_; s++){
    unsigned* act_c = flags + s*128;
    unsigned* chg_c = act_c + 64;
    unsigned* act_n = flags + (s+1)*128;
    unsigned* chg_n = act_n + 64;
    gemm128_kernel<1><<<64*12, 512, 0, stream>>>(stb, wqkv_t, bqkv, qkv, 12, 512, 1536,
                                                 vt, nullptr, 0, 0.f, nullptr, nullptr, nullptr,
                                                 nullptr, chg_c, act_c);
    attn_kernel<<<512, 256, 0, stream>>>(qkv, vt, ctx, act_c);
    gemm128_kernel<3><<<64*4, 512, 0, stream>>>(ctx, wo_t, bo, yb, 4, 512, 512,
                                                nullptr, nullptr, 0, 0.f, nullptr, nullptr, parts1,
                                                stb, act_c, nullptr);
    gemm128_kernel<4><<<64*16, 512, 0, stream>>>(yb, w1_t, b1, hbuf, 16, 512, 2048,
                                                 nullptr, parts1, 16, 1.f/512.f, G1, C1, parts2,
                                                 nullptr, act_c, nullptr);
    gemm128_kernel<5><<<64*4, 512, 0, stream>>>(hbuf, w2_t, b2, o2b, 4, 2048, 512,
                                                nullptr, parts2, 64, 1.f/2048.f, G2, C2, nullptr,
                                                nullptr, act_c, nullptr);
    ln2mix_kernel<<<M_/4, 256, 0, stream>>>(yb, o2b, parts1, ln1_g, ln1_b, ln2_g, ln2_b,
                                            aw, ab, st, stb, hp, rem, uw, act_n, chg_n);
  }
}

// Round 21
// 521.891 us; speedup vs baseline: 1.1337x; 1.0409x over previous
//
#include <hip/hip_runtime.h>
#include <cstdint>
#include <cstddef>

#define B_ 8
#define S_ 1024
#define D_ 512
#define H_ 8
#define DFF_ 2048
#define STEPS_ 6
#define M_ (B_*S_)   // 8192 tokens

typedef unsigned short u16;
typedef u16   u16x8 __attribute__((ext_vector_type(8)));
typedef short s16x8 __attribute__((ext_vector_type(8)));
typedef float f32x4 __attribute__((ext_vector_type(4)));
typedef float f32x16 __attribute__((ext_vector_type(16)));

__device__ __forceinline__ u16 f2b(float f){
  union { float f; unsigned u; } v; v.f = f;
  unsigned r = v.u + 0x7fffu + ((v.u >> 16) & 1u);
  return (u16)(r >> 16);
}
__device__ __forceinline__ float b2f(u16 u){
  union { unsigned u; float f; } v; v.u = ((unsigned)u) << 16;
  return v.f;
}
__device__ __forceinline__ unsigned cvtpk(float lo, float hi){
  unsigned r;
  asm("v_cvt_pk_bf16_f32 %0, %1, %2" : "=v"(r) : "v"(lo), "v"(hi));
  return r;
}
__device__ __forceinline__ void gload16(const void* g, void* l){
  __builtin_amdgcn_global_load_lds(
    (const __attribute__((address_space(1))) void*)g,
    (__attribute__((address_space(3))) void*)l, 16, 0, 0);
}
__device__ __forceinline__ float wred_sum(float v){
  #pragma unroll
  for (int m = 1; m < 64; m <<= 1) v += __shfl_xor(v, m, 64);
  return v;
}

// ---------------- prep: st = x, stb = bf16(x), initial halting state ----------------
__global__ __launch_bounds__(256) void prep_kernel(const float* __restrict__ x,
    const float* __restrict__ aw, const float* __restrict__ ab,
    float* __restrict__ st, u16* __restrict__ stb,
    float* __restrict__ hp, float* __restrict__ rem, float* __restrict__ uw){
  int tid = threadIdx.x; int l = tid & 63; int w = tid >> 6;
  size_t i = (size_t)blockIdx.x*256 + tid;     // one wave = one row
  const float4* xp = (const float4*)x + i*2;
  float4 a = xp[0], b = xp[1];
  ((float4*)st)[i*2]   = a;
  ((float4*)st)[i*2+1] = b;
  u16x8 o;
  o[0]=f2b(a.x); o[1]=f2b(a.y); o[2]=f2b(a.z); o[3]=f2b(a.w);
  o[4]=f2b(b.x); o[5]=f2b(b.y); o[6]=f2b(b.z); o[7]=f2b(b.w);
  ((u16x8*)stb)[i] = o;
  const float4* wp = (const float4*)aw + (size_t)l*2;
  float4 w0 = wp[0], w1 = wp[1];
  float d = a.x*w0.x + a.y*w0.y + a.z*w0.z + a.w*w0.w
          + b.x*w1.x + b.y*w1.y + b.z*w1.z + b.w*w1.w;
  d = wred_sum(d);
  if (l == 0){
    int row = blockIdx.x*4 + w;
    float t = d + ab[0];
    float p = 1.f / (1.f + expf(-t));
    // reference step with h=0, r=0
    float nh  = (p > 0.99f) ? 1.f : 0.f;
    float st2 = 1.f - nh;
    float h = p*st2;
    float r = nh*(1.f - h);
    h += nh*r;
    hp[row] = h; rem[row] = r;
    uw[row] = p*st2 + nh*r;
  }
}

// ---------------- tiled transpose-cast: W[K][N] f32 -> Wt[N][K] bf16, row-scaled ----------------
__global__ __launch_bounds__(256) void tcast_kernel(const float* __restrict__ W,
    u16* __restrict__ Wt, int K, int N, const float* __restrict__ scale){
  __shared__ u16 T[64*66];
  int tid = threadIdx.x;
  int nbt = N >> 6;
  int k0 = (blockIdx.x / nbt) << 6, n0 = (blockIdx.x % nbt) << 6;
  int r = tid >> 2, c4 = tid & 3;
  float sc = scale ? scale[k0 + r] : 1.f;
  const float* src = W + (size_t)(k0 + r)*N + n0 + c4*16;
  #pragma unroll
  for (int q = 0; q < 2; q++){
    float4 f0 = ((const float4*)src)[q*2], f1 = ((const float4*)src)[q*2+1];
    u16x8 t;
    t[0]=f2b(f0.x*sc); t[1]=f2b(f0.y*sc); t[2]=f2b(f0.z*sc); t[3]=f2b(f0.w*sc);
    t[4]=f2b(f1.x*sc); t[5]=f2b(f1.y*sc); t[6]=f2b(f1.z*sc); t[7]=f2b(f1.w*sc);
    *(u16x8*)&T[r*66 + c4*16 + q*8] = t;
  }
  __syncthreads();
  int n = tid >> 2;
  #pragma unroll
  for (int t2 = 0; t2 < 2; t2++){
    int sc2 = (tid & 3) + t2*4;
    u16x8 o;
    #pragma unroll
    for (int j = 0; j < 8; j++) o[j] = T[(sc2*8 + j)*66 + n];
    *(u16x8*)&Wt[(size_t)(n0 + n)*K + k0 + sc2*8] = o;
  }
}

// packb + per-step flag init: flags[step*128 + {0..63 act, 64..127 chg}], 7 slots
__global__ void packb_kernel(const float* __restrict__ bq, const float* __restrict__ bk,
                             const float* __restrict__ bv, float* __restrict__ bqkv,
                             unsigned* __restrict__ flags){
  int i = blockIdx.x*256 + threadIdx.x;
  if (i < 512)       bqkv[i] = bq[i];
  else if (i < 1024) bqkv[i] = bk[i-512];
  else if (i < 1536) bqkv[i] = bv[i-1024];
  if (i < 896) flags[i] = (i < 128) ? 1u : 0u;   // step 0 fully active/changed
}

// ---------------- G/C precompute (coalesced 2-stage) ----------------
__global__ __launch_bounds__(256) void gcpart_kernel(const float* __restrict__ W,
    const float* __restrict__ g, const float* __restrict__ be,
    float* __restrict__ pg, float* __restrict__ pc, int N){
  int kb = blockIdx.x, cb = blockIdx.y, t = threadIdx.x;
  __shared__ float gs[64], bs[64];
  if (t < 64){ gs[t] = g[kb*64 + t]; bs[t] = be[kb*64 + t]; }
  __syncthreads();
  int col = cb*256 + t;
  float ag = 0.f, ac = 0.f;
  #pragma unroll 8
  for (int k = 0; k < 64; k++){
    float w = W[(size_t)(kb*64 + k)*N + col];
    ag = fmaf(gs[k], w, ag);
    ac = fmaf(bs[k], w, ac);
  }
  pg[(size_t)kb*N + col] = ag;
  pc[(size_t)kb*N + col] = ac;
}

__global__ __launch_bounds__(256) void gcred_kernel(const float* __restrict__ pg,
    const float* __restrict__ pc, float* __restrict__ G, float* __restrict__ Cc,
    int np, int N){
  int col = blockIdx.x*256 + threadIdx.x;
  float sg = 0.f, sc = 0.f;
  for (int i = 0; i < np; i++){
    sg += pg[(size_t)i*N + col];
    sc += pc[(size_t)i*N + col];
  }
  G[col] = sg; Cc[col] = sc;
}

// ---------------- 128x128 GEMM, BK=64, 8 waves (512 thr), double-buffered ----------------
// parts layout: row-major parts[row][strip] (16 strips for wo, 64 for ffn1)
// EPI 1: qkv. Q-blocks (n0<512) gate on act[tm]; K/V blocks gate on chg[tm] && batch-active.
// EPI 3: wo:  y = acc + bias + resid(bf16 stb); bf16 out + parts[row][16]; skip by act
// EPI 4: ffn1: relu(LN-affine, stats from pin np=16); bf16 out + parts[row][64]; skip by act
// EPI 5: ffn2: LN-affine (stats from pin np=64); bf16 out; skip by act
template<int EPI>
__global__ __launch_bounds__(512, 4) void gemm128_kernel(
    const u16* __restrict__ A, const u16* __restrict__ Bt,
    const float* __restrict__ bias, void* __restrict__ C,
    int ntn, int K, int ldo, u16* __restrict__ vt,
    const float2* __restrict__ pin, int np, float invD,
    const float* __restrict__ gvec,
    const float* __restrict__ cvec, float2* __restrict__ parts,
    const u16* __restrict__ resid16, const unsigned* __restrict__ tflag,
    const unsigned* __restrict__ actarr){
  __shared__ u16 Als[2][128*64];
  __shared__ u16 Bls[2][128*64];
  __shared__ float2 srow[128];
  int tid = threadIdx.x, l = tid & 63, w = tid >> 6;   // w in [0,8)
  int hi = l >> 4, ln = l & 15;
  int wm = w >> 2, wn = w & 3;                 // 2M x 4N wave grid; wave out 64x32
  int nwg = gridDim.x;
  int bid = blockIdx.x;
  int swz = (bid & 7) * (nwg >> 3) + (bid >> 3);   // XCD-contiguous (nwg % 8 == 0)
  int tn = swz % ntn, tm = swz / ntn;
  int m0 = tm << 7, n0 = tn << 7;
  if (EPI == 1){
    if (n0 < 512){                             // Q: only for active q-tiles
      if (!actarr[tm]) return;
    } else {                                   // K/V: fresh + batch has active queries
      int b8 = (tm >> 3) << 3;
      unsigned ba = actarr[b8]   | actarr[b8+1] | actarr[b8+2] | actarr[b8+3]
                  | actarr[b8+4] | actarr[b8+5] | actarr[b8+6] | actarr[b8+7];
      if (!ba || !tflag[tm]) return;
    }
  } else {
    if (!tflag[tm]) return;                    // freeze skip (uniform)
  }
  int rl8 = l >> 3;
  int cg = (l & 7) ^ rl8;                      // pre-swizzled 16B chunk
  size_t aoff = (size_t)(m0 + w*8 + rl8)*K + cg*8;
  size_t boff = (size_t)(n0 + w*8 + rl8)*K + cg*8;
  int nt = K >> 6;

  f32x4 acc[4][2];
  #pragma unroll
  for (int i=0;i<4;i++)
    #pragma unroll
    for (int j=0;j<2;j++) acc[i][j] = (f32x4){0.f,0.f,0.f,0.f};

  // per buffer per thread: 2 A-loads + 2 B-loads; wave-load covers 8 rows x 64 cols
  #define G128(buf, kt) do { \
    size_t kof = (size_t)(kt)*64; \
    _Pragma("unroll") \
    for (int j = 0; j < 2; j++){ \
      gload16(A  + aoff + (size_t)j*64*K + kof, &Als[buf][(j*8 + w)*512]); \
      gload16(Bt + boff + (size_t)j*64*K + kof, &Bls[buf][(j*8 + w)*512]); \
    } } while(0)

  G128(0, 0);
  if (EPI == 4 || EPI == 5){
    // per-row LN stats: 4 threads/row, float4 loads, 2-step quad reduce
    int r = tid >> 2, qd = tid & 3;
    int per = np >> 2;                         // float2 per thread (4 or 16)
    const float2* pr = pin + (size_t)(m0 + r)*np + qd*per;
    float s = 0.f, q = 0.f;
    for (int p = 0; p < per; p += 2){
      float4 v = *(const float4*)(pr + p);
      s += v.x + v.z; q += v.y + v.w;
    }
    s += __shfl_xor(s, 1, 64); q += __shfl_xor(q, 1, 64);
    s += __shfl_xor(s, 2, 64); q += __shfl_xor(q, 2, 64);
    if (qd == 0){
      float mu = s*invD;
      float var = q*invD - mu*mu;
      srow[r] = make_float2(mu, rsqrtf(fmaxf(var, 0.f) + 1e-6f));
    }
  }
  __syncthreads();

  for (int t = 0; t < nt; t++){
    int cur = t & 1;
    if (t+1 < nt) G128(cur^1, t+1);            // prefetch into the OTHER buffer
    s16x8 af[4][2], bf[2][2];
    #pragma unroll
    for (int mi=0;mi<4;mi++){
      int row = wm*64 + mi*16 + ln;
      #pragma unroll
      for (int kk=0;kk<2;kk++)
        af[mi][kk] = *(const s16x8*)&Als[cur][row*64 + (((kk*4+hi)^(row&7))*8)];
    }
    #pragma unroll
    for (int ni=0;ni<2;ni++){
      int row = wn*32 + ni*16 + ln;
      #pragma unroll
      for (int kk=0;kk<2;kk++)
        bf[ni][kk] = *(const s16x8*)&Bls[cur][row*64 + (((kk*4+hi)^(row&7))*8)];
    }
    #pragma unroll
    for (int mi=0;mi<4;mi++)
      #pragma unroll
      for (int ni=0;ni<2;ni++)
        #pragma unroll
        for (int kk=0;kk<2;kk++)
          acc[mi][ni] = __builtin_amdgcn_mfma_f32_16x16x32_bf16(af[mi][kk], bf[ni][kk], acc[mi][ni], 0,0,0);
    if (t+1 < nt) __syncthreads();
  }
  #undef G128

  if (EPI == 1){
    if (n0 >= 1024){
      #pragma unroll
      for (int mi=0;mi<4;mi++){
        int row0 = m0 + wm*64 + mi*16 + hi*4;
        int b = row0 >> 10, s0 = row0 & 1023;
        #pragma unroll
        for (int ni=0;ni<2;ni++){
          int vcol = (n0 - 1024) + wn*32 + ni*16 + ln;
          int h = vcol >> 6, d = vcol & 63;
          float bc = bias[1024 + vcol];
          uint2 pk;
          pk.x = cvtpk(acc[mi][ni][0] + bc, acc[mi][ni][1] + bc);
          pk.y = cvtpk(acc[mi][ni][2] + bc, acc[mi][ni][3] + bc);
          *(uint2*)&vt[((size_t)((b*8 + h)*64 + d))*1024 + s0] = pk;
        }
      }
      return;
    }
    float qs = (n0 < 512) ? 0.125f : 1.0f;     // fold softmax scale into Q
    #pragma unroll
    for (int mi=0;mi<4;mi++){
      int row0 = m0 + wm*64 + mi*16 + hi*4;
      #pragma unroll
      for (int ni=0;ni<2;ni++){
        int col = n0 + wn*32 + ni*16 + ln;
        float bc = bias[col];
        #pragma unroll
        for (int r=0;r<4;r++)
          ((u16*)C)[(size_t)(row0+r)*ldo + col] = f2b((acc[mi][ni][r] + bc)*qs);
      }
    }
    return;
  }

  if (EPI == 3){
    float bv[2];
    #pragma unroll
    for (int ni=0;ni<2;ni++) bv[ni] = bias[n0 + wn*32 + ni*16 + ln];
    #pragma unroll
    for (int mi=0;mi<4;mi++){
      int row0 = m0 + wm*64 + mi*16 + hi*4;
      #pragma unroll
      for (int r=0;r<4;r++){
        int row = row0 + r;
        float s = 0.f, q = 0.f;
        #pragma unroll
        for (int ni=0;ni<2;ni++){
          int col = n0 + wn*32 + ni*16 + ln;
          float v = acc[mi][ni][r] + bv[ni] + b2f(resid16[(size_t)row*ldo + col]);
          ((u16*)C)[(size_t)row*ldo + col] = f2b(v);
          s += v; q += v*v;
        }
        #pragma unroll
        for (int msk=1;msk<16;msk<<=1){ s += __shfl_xor(s,msk,64); q += __shfl_xor(q,msk,64); }
        if (ln == 0) parts[(size_t)row*16 + (tn*4 + wn)] = make_float2(s, q);
      }
    }
    return;
  }

  // EPI 4 / 5
  {
    float gv[2], cv[2];
    #pragma unroll
    for (int ni=0;ni<2;ni++){
      int col = n0 + wn*32 + ni*16 + ln;
      gv[ni] = gvec[col];
      cv[ni] = cvec[col] + bias[col];
    }
    #pragma unroll
    for (int mi=0;mi<4;mi++){
      int lrow0 = wm*64 + mi*16 + hi*4;
      #pragma unroll
      for (int r=0;r<4;r++){
        int row = m0 + lrow0 + r;
        float2 sr = srow[lrow0 + r];
        float rmu = sr.y * sr.x;
        float s = 0.f, q = 0.f;
        #pragma unroll
        for (int ni=0;ni<2;ni++){
          int col = n0 + wn*32 + ni*16 + ln;
          float v = sr.y*acc[mi][ni][r] - rmu*gv[ni] + cv[ni];
          if (EPI == 4) v = fmaxf(v, 0.f);
          ((u16*)C)[(size_t)row*ldo + col] = f2b(v);
          s += v; q += v*v;
        }
        if (EPI == 4){
          #pragma unroll
          for (int msk=1;msk<16;msk<<=1){ s += __shfl_xor(s,msk,64); q += __shfl_xor(q,msk,64); }
          if (ln == 0) parts[(size_t)row*64 + (tn*4 + wn)] = make_float2(s, q);
        }
      }
    }
  }
}

// ---------------- flash attention, 32x32 MFMA, swapped QK^T, permlane P-redistribute ----------------
__global__ __launch_bounds__(256) void attn_kernel(const u16* __restrict__ qkv,
                                                   const u16* __restrict__ vt,
                                                   u16* __restrict__ ctx,
                                                   const unsigned* __restrict__ tfact){
  __shared__ u16 Ks[2][64*64];
  __shared__ u16 Vs[2][64*64];
  int tid = threadIdx.x, l = tid & 63, w = tid >> 6;
  int q5 = l & 31, hi2 = l >> 5;
  int orig = ((blockIdx.x & 7) << 6) | (blockIdx.x >> 3);   // XCD-contiguous: one b per XCD
  int qt = orig & 7, h = (orig >> 3) & 7, b = orig >> 6;
  if (!tfact[b*8 + qt]) return;                             // freeze skip (uniform)
  size_t rowbase = (size_t)b * S_;

  int qrow = qt*128 + w*32 + q5;
  s16x8 bq[4];
  #pragma unroll
  for (int dk = 0; dk < 4; dk++)
    bq[dk] = *(const s16x8*)&qkv[(rowbase + qrow)*1536 + h*64 + dk*16 + hi2*8];

  int rl = l >> 3;
  int cg = (l & 7) ^ rl;
  const u16* kb = qkv + rowbase*1536 + 512 + h*64 + cg*8;
  const u16* vb = vt + (size_t)((b*8 + h)*64)*1024 + cg*8;

  f32x16 o[2];
  #pragma unroll
  for (int mt = 0; mt < 2; mt++)
    #pragma unroll
    for (int r = 0; r < 16; r++) o[mt][r] = 0.f;
  float l_ = 0.f;

  #define STAGE(buf, kt) do { \
    _Pragma("unroll") \
    for (int r2 = 0; r2 < 2; r2++){ \
      int rr = r2*32 + w*8; \
      gload16(kb + (size_t)((kt)*64 + rr + rl)*1536, &Ks[buf][rr*64]); \
      gload16(vb + (size_t)(rr + rl)*1024 + (kt)*64, &Vs[buf][rr*64]); \
    } } while(0)

  STAGE(0, 0);
  STAGE(1, 1);
  asm volatile("s_waitcnt vmcnt(4)" ::: "memory");
  __builtin_amdgcn_s_barrier();
  __builtin_amdgcn_sched_barrier(0);

  for (int kt = 0; kt < 16; kt++){
    int cur = kt & 1;
    s16x8 ak[2][4], av[2][4];
    #pragma unroll
    for (int mt = 0; mt < 2; mt++){
      int r0 = mt*32 + q5;
      int sw = r0 & 7;
      #pragma unroll
      for (int dk = 0; dk < 4; dk++)
        ak[mt][dk] = *(const s16x8*)&Ks[cur][r0*64 + (((2*dk + hi2) ^ sw)*8)];
      #pragma unroll
      for (int ks = 0; ks < 4; ks++)
        av[mt][ks] = *(const s16x8*)&Vs[cur][r0*64 + (((2*ks + hi2) ^ sw)*8)];
    }
    asm volatile("s_waitcnt lgkmcnt(0)" ::: "memory");
    __builtin_amdgcn_sched_barrier(0);
    __builtin_amdgcn_s_barrier();
    __builtin_amdgcn_sched_barrier(0);
    if (kt < 14) STAGE(cur, kt+2);

    f32x16 sacc[2];
    #pragma unroll
    for (int mt = 0; mt < 2; mt++){
      f32x16 acc;
      #pragma unroll
      for (int r = 0; r < 16; r++) acc[r] = 0.f;
      #pragma unroll
      for (int dk = 0; dk < 4; dk++)
        acc = __builtin_amdgcn_mfma_f32_32x32x16_bf16(ak[mt][dk], bq[dk], acc, 0,0,0);
      sacc[mt] = acc;
    }

    float p[2][16];
    float rs = 0.f;
    #pragma unroll
    for (int mt = 0; mt < 2; mt++)
      #pragma unroll
      for (int r = 0; r < 16; r++){
        float e = __expf(sacc[mt][r]);
        p[mt][r] = e; rs += e;
      }
    rs += __shfl_xor(rs, 32, 64);
    l_ += rs;

    unsigned wds[4][4];
    #pragma unroll
    for (int ks = 0; ks < 4; ks++){
      const int mt = ks >> 1, base = (ks & 1)*8;
      unsigned a0 = cvtpk(p[mt][base+0], p[mt][base+1]);
      unsigned b0 = cvtpk(p[mt][base+4], p[mt][base+5]);
      asm("v_permlane32_swap_b32 %0, %1" : "+v"(a0), "+v"(b0));
      unsigned a1 = cvtpk(p[mt][base+2], p[mt][base+3]);
      unsigned b1 = cvtpk(p[mt][base+6], p[mt][base+7]);
      asm("v_permlane32_swap_b32 %0, %1" : "+v"(a1), "+v"(b1));
      wds[ks][0] = a0; wds[ks][1] = a1; wds[ks][2] = b0; wds[ks][3] = b1;
    }

    #pragma unroll
    for (int ks = 0; ks < 4; ks++){
      union { unsigned u[4]; s16x8 v; } bp;
      bp.u[0] = wds[ks][0]; bp.u[1] = wds[ks][1];
      bp.u[2] = wds[ks][2]; bp.u[3] = wds[ks][3];
      #pragma unroll
      for (int mt = 0; mt < 2; mt++)
        o[mt] = __builtin_amdgcn_mfma_f32_32x32x16_bf16(av[mt][ks], bp.v, o[mt], 0,0,0);
    }

    if (kt < 15){
      if (kt < 14) asm volatile("s_waitcnt vmcnt(4)" ::: "memory");
      else         asm volatile("s_waitcnt vmcnt(0)" ::: "memory");
      __builtin_amdgcn_s_barrier();
      __builtin_amdgcn_sched_barrier(0);
    }
  }
  #undef STAGE

  __builtin_amdgcn_s_barrier();
  float inv = 1.f / l_;
  u16* ob = ((w < 2) ? (u16*)Ks : (u16*)Vs) + (w & 1)*2304;
  #pragma unroll
  for (int mt = 0; mt < 2; mt++)
    #pragma unroll
    for (int g = 0; g < 4; g++)
      #pragma unroll
      for (int p2 = 0; p2 < 2; p2++){
        unsigned wd = cvtpk(o[mt][g*4 + p2*2]*inv, o[mt][g*4 + p2*2 + 1]*inv);
        int d0 = mt*32 + g*8 + hi2*4 + p2*2;
        *(unsigned*)&ob[q5*72 + d0] = wd;
      }
  asm volatile("s_waitcnt lgkmcnt(0)" ::: "memory");
  __builtin_amdgcn_sched_barrier(0);
  int r2 = l >> 1, cb = (l & 1)*32;
  size_t row = rowbase + qt*128 + w*32 + r2;
  #pragma unroll
  for (int c = 0; c < 4; c++){
    uint4 v = *(uint4*)&ob[r2*72 + cb + c*8];
    *(uint4*)&ctx[row*512 + h*64 + cb + c*8] = v;
  }
}

// ---------------- LN2 + ACT mix + next-step halting update (4 rows / 256-thr block) ----------------
__global__ __launch_bounds__(256) void ln2mix_kernel(
    const u16* __restrict__ yb, const u16* __restrict__ o2b,
    const float2* __restrict__ parts1,
    const float* __restrict__ g1, const float* __restrict__ be1,
    const float* __restrict__ g, const float* __restrict__ bt,
    const float* __restrict__ aw, const float* __restrict__ ab,
    float* __restrict__ st, u16* __restrict__ stb,
    float* __restrict__ hp, float* __restrict__ rem, float* __restrict__ uw,
    unsigned* __restrict__ tfact_next, unsigned* __restrict__ tfchg_next){
  int lane = threadIdx.x & 63;
  int row = blockIdx.x*4 + (threadIdx.x >> 6);
  float u = uw[row];
  if (u == 0.f) return;              // frozen at this step's entry: exact no-op (per-wave)
  size_t base = (size_t)row*512 + lane*8;
  // row stats from wo partials (16 consecutive strips of this row)
  float2 pp = parts1[(size_t)row*16 + (lane & 15)];
  float ps = pp.x, pq = pp.y;
  #pragma unroll
  for (int msk=1;msk<16;msk<<=1){ ps += __shfl_xor(ps,msk,64); pq += __shfl_xor(pq,msk,64); }
  float mu1 = ps*(1.f/512.f);
  float var1 = pq*(1.f/512.f) - mu1*mu1;
  float rstd1 = rsqrtf(fmaxf(var1, 0.f) + 1e-6f);
  int c0 = lane*8;
  float v[8], sv[8];
  {
    u16x8 y8 = *(const u16x8*)(yb + base);
    u16x8 o8 = *(const u16x8*)(o2b + base);
    const float4* sp = (const float4*)(st + base);
    float4 s0 = sp[0], s1f = sp[1];
    #pragma unroll
    for (int j=0;j<8;j++){
      float out1 = (b2f(y8[j]) - mu1)*rstd1*g1[c0+j] + be1[c0+j];
      v[j] = out1 + b2f(o8[j]);
    }
    sv[0]=s0.x; sv[1]=s0.y; sv[2]=s0.z; sv[3]=s0.w;
    sv[4]=s1f.x; sv[5]=s1f.y; sv[6]=s1f.z; sv[7]=s1f.w;
  }
  float sum=0.f, sq=0.f;
  #pragma unroll
  for (int j=0;j<8;j++){ sum += v[j]; sq += v[j]*v[j]; }
  sum = wred_sum(sum); sq = wred_sum(sq);
  float mean = sum*(1.f/512.f);
  float var  = sq*(1.f/512.f) - mean*mean;
  float rstd = rsqrtf(fmaxf(var, 0.f) + 1e-6f);
  float um1 = 1.f - u;
  float z[8]; u16x8 ob;
  #pragma unroll
  for (int j=0;j<8;j++){
    float y = (v[j]-mean)*rstd*g[c0+j] + bt[c0+j];
    z[j] = y*u + sv[j]*um1;
    ob[j] = f2b(z[j]);
  }
  float4* op = (float4*)(st + base);
  op[0] = make_float4(z[0],z[1],z[2],z[3]);
  op[1] = make_float4(z[4],z[5],z[6],z[7]);
  *(u16x8*)(stb + base) = ob;
  const float4* wp = (const float4*)aw + (size_t)lane*2;
  float4 w0 = wp[0], w1 = wp[1];
  float d = z[0]*w0.x + z[1]*w0.y + z[2]*w0.z + z[3]*w0.w
          + z[4]*w1.x + z[5]*w1.y + z[6]*w1.z + z[7]*w1.w;
  d = wred_sum(d);
  if (lane == 0){
    float t = d + ab[0];
    float p = 1.f / (1.f + expf(-t));
    float h = hp[row], r = rem[row];
    bool active_next = (h < 1.f);    // uw_{s+1} != 0 iff this (pre-update) h < 1
    float still = active_next ? 1.f : 0.f;
    float cand  = h + p*still;
    float nh  = (cand > 0.99f)  ? still : 0.f;
    float st2 = (cand <= 0.99f) ? still : 0.f;
    h += p*st2;
    r += nh*(1.f - h);
    h += nh*r;
    hp[row] = h; rem[row] = r;
    uw[row] = p*st2 + nh*r;
    // idempotent flag set: plain stores (fresh per-step slot, zeroed once at init)
    tfchg_next[row >> 7] = 1u;
    if (active_next) tfact_next[row >> 7] = 1u;
  }
}

// ---------------- host launch ----------------
extern "C" void kernel_launch(void* const* d_in, const int* in_sizes, int n_in,
                              void* d_out, int out_size, void* d_ws, size_t ws_size,
                              hipStream_t stream){
  const float* x     = (const float*)d_in[0];
  const float* wq    = (const float*)d_in[1];
  const float* bq    = (const float*)d_in[2];
  const float* wk    = (const float*)d_in[3];
  const float* bk    = (const float*)d_in[4];
  const float* wv    = (const float*)d_in[5];
  const float* bv    = (const float*)d_in[6];
  const float* wo    = (const float*)d_in[7];
  const float* bo    = (const float*)d_in[8];
  const float* w1    = (const float*)d_in[9];
  const float* b1    = (const float*)d_in[10];
  const float* lnf_g = (const float*)d_in[11];
  const float* lnf_b = (const float*)d_in[12];
  const float* w2    = (const float*)d_in[13];
  const float* b2    = (const float*)d_in[14];
  const float* ln1_g = (const float*)d_in[15];
  const float* ln1_b = (const float*)d_in[16];
  const float* ln2_g = (const float*)d_in[17];
  const float* ln2_b = (const float*)d_in[18];
  const float* aw    = (const float*)d_in[19];
  const float* ab    = (const float*)d_in[20];
  float* st = (float*)d_out;

  char* cur = (char*)d_ws;
  auto alloc = [&](size_t n){ void* p = cur; cur += (n + 255) & ~(size_t)255; return p; };
  u16*  wqkv_t = (u16*)alloc((size_t)1536*512*2);
  u16*  wo_t   = (u16*)alloc((size_t)512*512*2);
  u16*  w1_t   = (u16*)alloc((size_t)2048*512*2);   // ln1_g-scaled
  u16*  w2_t   = (u16*)alloc((size_t)512*2048*2);   // lnf_g-scaled
  float* bqkv  = (float*)alloc(1536*4);
  float* G1    = (float*)alloc(2048*4);
  float* C1    = (float*)alloc(2048*4);
  float* G2    = (float*)alloc(512*4);
  float* C2    = (float*)alloc(512*4);
  float* pg    = (float*)alloc((size_t)16384*4);
  float* pc    = (float*)alloc((size_t)16384*4);
  u16*  stb    = (u16*)alloc((size_t)M_*512*2);
  u16*  qkv    = (u16*)alloc((size_t)M_*1536*2);
  u16*  vt     = (u16*)alloc((size_t)M_*512*2);     // persistent transposed V
  u16*  ctx    = (u16*)alloc((size_t)M_*512*2);
  u16*  yb     = (u16*)alloc((size_t)M_*512*2);
  u16*  o2b    = (u16*)alloc((size_t)M_*512*2);
  u16*  hbuf   = (u16*)alloc((size_t)M_*2048*2);
  float2* parts1 = (float2*)alloc((size_t)M_*16*8);   // [row][16]
  float2* parts2 = (float2*)alloc((size_t)M_*64*8);   // [row][64]
  float* halt  = (float*)alloc((size_t)3*M_*4);
  unsigned* flags = (unsigned*)alloc(896*4);        // 7 steps x {act[64], chg[64]}
  float* hp = halt, *rem = halt + M_, *uw = halt + 2*M_;

  prep_kernel<<<2048, 256, 0, stream>>>(x, aw, ab, st, stb, hp, rem, uw);
  packb_kernel<<<6, 256, 0, stream>>>(bq, bk, bv, bqkv, flags);
  tcast_kernel<<<64,  256, 0, stream>>>(wq, wqkv_t,            512, 512, nullptr);
  tcast_kernel<<<64,  256, 0, stream>>>(wk, wqkv_t + 512*512,  512, 512, nullptr);
  tcast_kernel<<<64,  256, 0, stream>>>(wv, wqkv_t + 1024*512, 512, 512, nullptr);
  tcast_kernel<<<64,  256, 0, stream>>>(wo, wo_t, 512, 512, nullptr);
  tcast_kernel<<<256, 256, 0, stream>>>(w1, w1_t, 512, 2048, ln1_g);
  tcast_kernel<<<256, 256, 0, stream>>>(w2, w2_t, 2048, 512, lnf_g);
  gcpart_kernel<<<dim3(8, 8),  256, 0, stream>>>(w1, ln1_g, ln1_b, pg, pc, 2048);
  gcred_kernel<<<8, 256, 0, stream>>>(pg, pc, G1, C1, 8, 2048);
  gcpart_kernel<<<dim3(32, 2), 256, 0, stream>>>(w2, lnf_g, lnf_b, pg, pc, 512);
  gcred_kernel<<<2, 256, 0, stream>>>(pg, pc, G2, C2, 32, 512);

  for (int s = 0; s < STEPS_; s++){
    unsigned* act_c = flags + s*128;
    unsigned* chg_c = act_c + 64;
    unsigned* act_n = flags + (s+1)*128;
    unsigned* chg_n = act_n + 64;
    gemm128_kernel<1><<<64*12, 512, 0, stream>>>(stb, wqkv_t, bqkv, qkv, 12, 512, 1536,
                                                 vt, nullptr, 0, 0.f, nullptr, nullptr, nullptr,
                                                 nullptr, chg_c, act_c);
    attn_kernel<<<512, 256, 0, stream>>>(qkv, vt, ctx, act_c);
    gemm128_kernel<3><<<64*4, 512, 0, stream>>>(ctx, wo_t, bo, yb, 4, 512, 512,
                                                nullptr, nullptr, 0, 0.f, nullptr, nullptr, parts1,
                                                stb, act_c, nullptr);
    gemm128_kernel<4><<<64*16, 512, 0, stream>>>(yb, w1_t, b1, hbuf, 16, 512, 2048,
                                                 nullptr, parts1, 16, 1.f/512.f, G1, C1, parts2,
                                                 nullptr, act_c, nullptr);
    gemm128_kernel<5><<<64*4, 512, 0, stream>>>(hbuf, w2_t, b2, o2b, 4, 2048, 512,
                                                nullptr, parts2, 64, 1.f/2048.f, G2, C2, nullptr,
                                                nullptr, act_c, nullptr);
    ln2mix_kernel<<<M_/4, 256, 0, stream>>>(yb, o2b, parts1, ln1_g, ln1_b, ln2_g, ln2_b,
                                            aw, ab, st, stb, hp, rem, uw, act_n, chg_n);
  }
}

// Round 22
// 521.240 us; speedup vs baseline: 1.1351x; 1.0012x over previous
//
#include <hip/hip_runtime.h>
#include <cstdint>
#include <cstddef>

#define B_ 8
#define S_ 1024
#define D_ 512
#define H_ 8
#define DFF_ 2048
#define STEPS_ 6
#define M_ (B_*S_)   // 8192 tokens

typedef unsigned short u16;
typedef u16   u16x8 __attribute__((ext_vector_type(8)));
typedef short s16x8 __attribute__((ext_vector_type(8)));
typedef float f32x4 __attribute__((ext_vector_type(4)));
typedef float f32x16 __attribute__((ext_vector_type(16)));

__device__ __forceinline__ u16 f2b(float f){
  union { float f; unsigned u; } v; v.f = f;
  unsigned r = v.u + 0x7fffu + ((v.u >> 16) & 1u);
  return (u16)(r >> 16);
}
__device__ __forceinline__ float b2f(u16 u){
  union { unsigned u; float f; } v; v.u = ((unsigned)u) << 16;
  return v.f;
}
__device__ __forceinline__ unsigned cvtpk(float lo, float hi){
  unsigned r;
  asm("v_cvt_pk_bf16_f32 %0, %1, %2" : "=v"(r) : "v"(lo), "v"(hi));
  return r;
}
__device__ __forceinline__ void gload16(const void* g, void* l){
  __builtin_amdgcn_global_load_lds(
    (const __attribute__((address_space(1))) void*)g,
    (__attribute__((address_space(3))) void*)l, 16, 0, 0);
}
__device__ __forceinline__ float wred_sum(float v){
  #pragma unroll
  for (int m = 1; m < 64; m <<= 1) v += __shfl_xor(v, m, 64);
  return v;
}

// ---------------- prep: st = x, stb = bf16(x), initial halting state ----------------
__global__ __launch_bounds__(256) void prep_kernel(const float* __restrict__ x,
    const float* __restrict__ aw, const float* __restrict__ ab,
    float* __restrict__ st, u16* __restrict__ stb,
    float* __restrict__ hp, float* __restrict__ rem, float* __restrict__ uw){
  int tid = threadIdx.x; int l = tid & 63; int w = tid >> 6;
  size_t i = (size_t)blockIdx.x*256 + tid;     // one wave = one row
  const float4* xp = (const float4*)x + i*2;
  float4 a = xp[0], b = xp[1];
  ((float4*)st)[i*2]   = a;
  ((float4*)st)[i*2+1] = b;
  u16x8 o;
  o[0]=f2b(a.x); o[1]=f2b(a.y); o[2]=f2b(a.z); o[3]=f2b(a.w);
  o[4]=f2b(b.x); o[5]=f2b(b.y); o[6]=f2b(b.z); o[7]=f2b(b.w);
  ((u16x8*)stb)[i] = o;
  const float4* wp = (const float4*)aw + (size_t)l*2;
  float4 w0 = wp[0], w1 = wp[1];
  float d = a.x*w0.x + a.y*w0.y + a.z*w0.z + a.w*w0.w
          + b.x*w1.x + b.y*w1.y + b.z*w1.z + b.w*w1.w;
  d = wred_sum(d);
  if (l == 0){
    int row = blockIdx.x*4 + w;
    float t = d + ab[0];
    float p = 1.f / (1.f + expf(-t));
    // reference step with h=0, r=0
    float nh  = (p > 0.99f) ? 1.f : 0.f;
    float st2 = 1.f - nh;
    float h = p*st2;
    float r = nh*(1.f - h);
    h += nh*r;
    hp[row] = h; rem[row] = r;
    uw[row] = p*st2 + nh*r;
  }
}

// ---------------- tiled transpose-cast: W[K][N] f32 -> Wt[N][K] bf16, row-scaled ----------------
__global__ __launch_bounds__(256) void tcast_kernel(const float* __restrict__ W,
    u16* __restrict__ Wt, int K, int N, const float* __restrict__ scale){
  __shared__ u16 T[64*66];
  int tid = threadIdx.x;
  int nbt = N >> 6;
  int k0 = (blockIdx.x / nbt) << 6, n0 = (blockIdx.x % nbt) << 6;
  int r = tid >> 2, c4 = tid & 3;
  float sc = scale ? scale[k0 + r] : 1.f;
  const float* src = W + (size_t)(k0 + r)*N + n0 + c4*16;
  #pragma unroll
  for (int q = 0; q < 2; q++){
    float4 f0 = ((const float4*)src)[q*2], f1 = ((const float4*)src)[q*2+1];
    u16x8 t;
    t[0]=f2b(f0.x*sc); t[1]=f2b(f0.y*sc); t[2]=f2b(f0.z*sc); t[3]=f2b(f0.w*sc);
    t[4]=f2b(f1.x*sc); t[5]=f2b(f1.y*sc); t[6]=f2b(f1.z*sc); t[7]=f2b(f1.w*sc);
    *(u16x8*)&T[r*66 + c4*16 + q*8] = t;
  }
  __syncthreads();
  int n = tid >> 2;
  #pragma unroll
  for (int t2 = 0; t2 < 2; t2++){
    int sc2 = (tid & 3) + t2*4;
    u16x8 o;
    #pragma unroll
    for (int j = 0; j < 8; j++) o[j] = T[(sc2*8 + j)*66 + n];
    *(u16x8*)&Wt[(size_t)(n0 + n)*K + k0 + sc2*8] = o;
  }
}

// packb + per-step flag init: flags[step*128 + {0..63 act, 64..127 chg}], 7 slots
__global__ void packb_kernel(const float* __restrict__ bq, const float* __restrict__ bk,
                             const float* __restrict__ bv, float* __restrict__ bqkv,
                             unsigned* __restrict__ flags){
  int i = blockIdx.x*256 + threadIdx.x;
  if (i < 512)       bqkv[i] = bq[i];
  else if (i < 1024) bqkv[i] = bk[i-512];
  else if (i < 1536) bqkv[i] = bv[i-1024];
  if (i < 896) flags[i] = (i < 128) ? 1u : 0u;   // step 0 fully active/changed
}

// ---------------- G/C precompute (coalesced 2-stage) ----------------
__global__ __launch_bounds__(256) void gcpart_kernel(const float* __restrict__ W,
    const float* __restrict__ g, const float* __restrict__ be,
    float* __restrict__ pg, float* __restrict__ pc, int N){
  int kb = blockIdx.x, cb = blockIdx.y, t = threadIdx.x;
  __shared__ float gs[64], bs[64];
  if (t < 64){ gs[t] = g[kb*64 + t]; bs[t] = be[kb*64 + t]; }
  __syncthreads();
  int col = cb*256 + t;
  float ag = 0.f, ac = 0.f;
  #pragma unroll 8
  for (int k = 0; k < 64; k++){
    float w = W[(size_t)(kb*64 + k)*N + col];
    ag = fmaf(gs[k], w, ag);
    ac = fmaf(bs[k], w, ac);
  }
  pg[(size_t)kb*N + col] = ag;
  pc[(size_t)kb*N + col] = ac;
}

__global__ __launch_bounds__(256) void gcred_kernel(const float* __restrict__ pg,
    const float* __restrict__ pc, float* __restrict__ G, float* __restrict__ Cc,
    int np, int N){
  int col = blockIdx.x*256 + threadIdx.x;
  float sg = 0.f, sc = 0.f;
  for (int i = 0; i < np; i++){
    sg += pg[(size_t)i*N + col];
    sc += pc[(size_t)i*N + col];
  }
  G[col] = sg; Cc[col] = sc;
}

// ---------------- 128x128 GEMM, BK=64, 8 waves (512 thr), double-buffered ----------------
// parts layout: row-major parts[row][strip] (16 strips for wo, 64 for ffn1)
// EPI 1: qkv. Q-blocks (n0<512) gate on act[tm]; K/V blocks gate on chg[tm] && batch-active.
//        V-blocks (n0>=1024) write transposed vt via per-wave LDS bounce (coalesced).
// EPI 3: wo:  y = acc + bias + resid(bf16 stb); bf16 out + parts[row][16]; skip by act
// EPI 4: ffn1: relu(LN-affine, stats from pin np=16); bf16 out + parts[row][64]; skip by act
// EPI 5: ffn2: LN-affine (stats from pin np=64); bf16 out; skip by act
template<int EPI>
__global__ __launch_bounds__(512, 4) void gemm128_kernel(
    const u16* __restrict__ A, const u16* __restrict__ Bt,
    const float* __restrict__ bias, void* __restrict__ C,
    int ntn, int K, int ldo, u16* __restrict__ vt,
    const float2* __restrict__ pin, int np, float invD,
    const float* __restrict__ gvec,
    const float* __restrict__ cvec, float2* __restrict__ parts,
    const u16* __restrict__ resid16, const unsigned* __restrict__ tflag,
    const unsigned* __restrict__ actarr){
  __shared__ u16 Als[2][128*64];
  __shared__ u16 Bls[2][128*64];
  __shared__ float2 srow[128];
  int tid = threadIdx.x, l = tid & 63, w = tid >> 6;   // w in [0,8)
  int hi = l >> 4, ln = l & 15;
  int wm = w >> 2, wn = w & 3;                 // 2M x 4N wave grid; wave out 64x32
  int nwg = gridDim.x;
  int bid = blockIdx.x;
  int swz = (bid & 7) * (nwg >> 3) + (bid >> 3);   // XCD-contiguous (nwg % 8 == 0)
  int tn = swz % ntn, tm = swz / ntn;
  int m0 = tm << 7, n0 = tn << 7;
  if (EPI == 1){
    if (n0 < 512){                             // Q: only for active q-tiles
      if (!actarr[tm]) return;
    } else {                                   // K/V: fresh + batch has active queries
      int b8 = (tm >> 3) << 3;
      unsigned ba = actarr[b8]   | actarr[b8+1] | actarr[b8+2] | actarr[b8+3]
                  | actarr[b8+4] | actarr[b8+5] | actarr[b8+6] | actarr[b8+7];
      if (!ba || !tflag[tm]) return;
    }
  } else {
    if (!tflag[tm]) return;                    // freeze skip (uniform)
  }
  int rl8 = l >> 3;
  int cg = (l & 7) ^ rl8;                      // pre-swizzled 16B chunk
  size_t aoff = (size_t)(m0 + w*8 + rl8)*K + cg*8;
  size_t boff = (size_t)(n0 + w*8 + rl8)*K + cg*8;
  int nt = K >> 6;

  f32x4 acc[4][2];
  #pragma unroll
  for (int i=0;i<4;i++)
    #pragma unroll
    for (int j=0;j<2;j++) acc[i][j] = (f32x4){0.f,0.f,0.f,0.f};

  // per buffer per thread: 2 A-loads + 2 B-loads; wave-load covers 8 rows x 64 cols
  #define G128(buf, kt) do { \
    size_t kof = (size_t)(kt)*64; \
    _Pragma("unroll") \
    for (int j = 0; j < 2; j++){ \
      gload16(A  + aoff + (size_t)j*64*K + kof, &Als[buf][(j*8 + w)*512]); \
      gload16(Bt + boff + (size_t)j*64*K + kof, &Bls[buf][(j*8 + w)*512]); \
    } } while(0)

  G128(0, 0);
  if (EPI == 4 || EPI == 5){
    // per-row LN stats: 4 threads/row, float4 loads, 2-step quad reduce
    int r = tid >> 2, qd = tid & 3;
    int per = np >> 2;                         // float2 per thread (4 or 16)
    const float2* pr = pin + (size_t)(m0 + r)*np + qd*per;
    float s = 0.f, q = 0.f;
    for (int p = 0; p < per; p += 2){
      float4 v = *(const float4*)(pr + p);
      s += v.x + v.z; q += v.y + v.w;
    }
    s += __shfl_xor(s, 1, 64); q += __shfl_xor(q, 1, 64);
    s += __shfl_xor(s, 2, 64); q += __shfl_xor(q, 2, 64);
    if (qd == 0){
      float mu = s*invD;
      float var = q*invD - mu*mu;
      srow[r] = make_float2(mu, rsqrtf(fmaxf(var, 0.f) + 1e-6f));
    }
  }
  __syncthreads();

  for (int t = 0; t < nt; t++){
    int cur = t & 1;
    if (t+1 < nt) G128(cur^1, t+1);            // prefetch into the OTHER buffer
    s16x8 af[4][2], bf[2][2];
    #pragma unroll
    for (int mi=0;mi<4;mi++){
      int row = wm*64 + mi*16 + ln;
      #pragma unroll
      for (int kk=0;kk<2;kk++)
        af[mi][kk] = *(const s16x8*)&Als[cur][row*64 + (((kk*4+hi)^(row&7))*8)];
    }
    #pragma unroll
    for (int ni=0;ni<2;ni++){
      int row = wn*32 + ni*16 + ln;
      #pragma unroll
      for (int kk=0;kk<2;kk++)
        bf[ni][kk] = *(const s16x8*)&Bls[cur][row*64 + (((kk*4+hi)^(row&7))*8)];
    }
    #pragma unroll
    for (int mi=0;mi<4;mi++)
      #pragma unroll
      for (int ni=0;ni<2;ni++)
        #pragma unroll
        for (int kk=0;kk<2;kk++)
          acc[mi][ni] = __builtin_amdgcn_mfma_f32_16x16x32_bf16(af[mi][kk], bf[ni][kk], acc[mi][ni], 0,0,0);
    if (t+1 < nt) __syncthreads();
  }
  #undef G128

  if (EPI == 1){
    if (n0 >= 1024){
      // -------- V-blocks: LDS-bounce transpose, coalesced vt writes --------
      __syncthreads();                         // all waves done with K-loop LDS
      unsigned* lw4 = (unsigned*)(((u16*)Als) + w*2048);  // per-wave [32 d][64 s], 4B-XOR-swizzled
      #pragma unroll
      for (int mi=0;mi<4;mi++){
        int sl2 = (mi*16 + hi*4) >> 1;         // 4B-chunk base (even)
        #pragma unroll
        for (int ni=0;ni<2;ni++){
          int dl = ni*16 + ln;                 // local d 0..31
          float bc = bias[1024 + (n0 - 1024) + wn*32 + ni*16 + ln];
          unsigned p0 = cvtpk(acc[mi][ni][0] + bc, acc[mi][ni][1] + bc);
          unsigned p1 = cvtpk(acc[mi][ni][2] + bc, acc[mi][ni][3] + bc);
          lw4[dl*32 + ( sl2      ^ dl)] = p0;
          lw4[dl*32 + ((sl2 + 1) ^ dl)] = p1;
        }
      }
      asm volatile("s_waitcnt lgkmcnt(0)" ::: "memory");
      __builtin_amdgcn_sched_barrier(0);
      int d_r = l >> 1, sh = l & 1;            // 2 lanes per d-row
      int vcol = (n0 - 1024) + wn*32 + d_r;
      int hh = vcol >> 6, dd = vcol & 63;
      int bb = m0 >> 10;                       // tile fits within one batch (128 | 1024)
      int s0g = (m0 & 1023) + wm*64 + sh*32;
      u16* dst = vt + ((size_t)((bb*8 + hh)*64 + dd))*1024 + s0g;
      #pragma unroll
      for (int c4 = 0; c4 < 4; c4++){
        uint4 ov;
        ov.x = lw4[d_r*32 + ((sh*16 + c4*4 + 0) ^ d_r)];
        ov.y = lw4[d_r*32 + ((sh*16 + c4*4 + 1) ^ d_r)];
        ov.z = lw4[d_r*32 + ((sh*16 + c4*4 + 2) ^ d_r)];
        ov.w = lw4[d_r*32 + ((sh*16 + c4*4 + 3) ^ d_r)];
        *(uint4*)(dst + c4*8) = ov;            // 16B contiguous; 64B/lane total
      }
      return;
    }
    float qs = (n0 < 512) ? 0.125f : 1.0f;     // fold softmax scale into Q
    #pragma unroll
    for (int mi=0;mi<4;mi++){
      int row0 = m0 + wm*64 + mi*16 + hi*4;
      #pragma unroll
      for (int ni=0;ni<2;ni++){
        int col = n0 + wn*32 + ni*16 + ln;
        float bc = bias[col];
        #pragma unroll
        for (int r=0;r<4;r++)
          ((u16*)C)[(size_t)(row0+r)*ldo + col] = f2b((acc[mi][ni][r] + bc)*qs);
      }
    }
    return;
  }

  if (EPI == 3){
    float bv[2];
    #pragma unroll
    for (int ni=0;ni<2;ni++) bv[ni] = bias[n0 + wn*32 + ni*16 + ln];
    #pragma unroll
    for (int mi=0;mi<4;mi++){
      int row0 = m0 + wm*64 + mi*16 + hi*4;
      #pragma unroll
      for (int r=0;r<4;r++){
        int row = row0 + r;
        float s = 0.f, q = 0.f;
        #pragma unroll
        for (int ni=0;ni<2;ni++){
          int col = n0 + wn*32 + ni*16 + ln;
          float v = acc[mi][ni][r] + bv[ni] + b2f(resid16[(size_t)row*ldo + col]);
          ((u16*)C)[(size_t)row*ldo + col] = f2b(v);
          s += v; q += v*v;
        }
        #pragma unroll
        for (int msk=1;msk<16;msk<<=1){ s += __shfl_xor(s,msk,64); q += __shfl_xor(q,msk,64); }
        if (ln == 0) parts[(size_t)row*16 + (tn*4 + wn)] = make_float2(s, q);
      }
    }
    return;
  }

  // EPI 4 / 5
  {
    float gv[2], cv[2];
    #pragma unroll
    for (int ni=0;ni<2;ni++){
      int col = n0 + wn*32 + ni*16 + ln;
      gv[ni] = gvec[col];
      cv[ni] = cvec[col] + bias[col];
    }
    #pragma unroll
    for (int mi=0;mi<4;mi++){
      int lrow0 = wm*64 + mi*16 + hi*4;
      #pragma unroll
      for (int r=0;r<4;r++){
        int row = m0 + lrow0 + r;
        float2 sr = srow[lrow0 + r];
        float rmu = sr.y * sr.x;
        float s = 0.f, q = 0.f;
        #pragma unroll
        for (int ni=0;ni<2;ni++){
          int col = n0 + wn*32 + ni*16 + ln;
          float v = sr.y*acc[mi][ni][r] - rmu*gv[ni] + cv[ni];
          if (EPI == 4) v = fmaxf(v, 0.f);
          ((u16*)C)[(size_t)row*ldo + col] = f2b(v);
          s += v; q += v*v;
        }
        if (EPI == 4){
          #pragma unroll
          for (int msk=1;msk<16;msk<<=1){ s += __shfl_xor(s,msk,64); q += __shfl_xor(q,msk,64); }
          if (ln == 0) parts[(size_t)row*64 + (tn*4 + wn)] = make_float2(s, q);
        }
      }
    }
  }
}

// ---------------- flash attention, 32x32 MFMA, swapped QK^T, permlane P-redistribute ----------------
__global__ __launch_bounds__(256) void attn_kernel(const u16* __restrict__ qkv,
                                                   const u16* __restrict__ vt,
                                                   u16* __restrict__ ctx,
                                                   const unsigned* __restrict__ tfact){
  __shared__ u16 Ks[2][64*64];
  __shared__ u16 Vs[2][64*64];
  int tid = threadIdx.x, l = tid & 63, w = tid >> 6;
  int q5 = l & 31, hi2 = l >> 5;
  int orig = ((blockIdx.x & 7) << 6) | (blockIdx.x >> 3);   // XCD-contiguous: one b per XCD
  int qt = orig & 7, h = (orig >> 3) & 7, b = orig >> 6;
  if (!tfact[b*8 + qt]) return;                             // freeze skip (uniform)
  size_t rowbase = (size_t)b * S_;

  int qrow = qt*128 + w*32 + q5;
  s16x8 bq[4];
  #pragma unroll
  for (int dk = 0; dk < 4; dk++)
    bq[dk] = *(const s16x8*)&qkv[(rowbase + qrow)*1536 + h*64 + dk*16 + hi2*8];

  int rl = l >> 3;
  int cg = (l & 7) ^ rl;
  const u16* kb = qkv + rowbase*1536 + 512 + h*64 + cg*8;
  const u16* vb = vt + (size_t)((b*8 + h)*64)*1024 + cg*8;

  f32x16 o[2];
  #pragma unroll
  for (int mt = 0; mt < 2; mt++)
    #pragma unroll
    for (int r = 0; r < 16; r++) o[mt][r] = 0.f;
  float l_ = 0.f;

  #define STAGE(buf, kt) do { \
    _Pragma("unroll") \
    for (int r2 = 0; r2 < 2; r2++){ \
      int rr = r2*32 + w*8; \
      gload16(kb + (size_t)((kt)*64 + rr + rl)*1536, &Ks[buf][rr*64]); \
      gload16(vb + (size_t)(rr + rl)*1024 + (kt)*64, &Vs[buf][rr*64]); \
    } } while(0)

  STAGE(0, 0);
  STAGE(1, 1);
  asm volatile("s_waitcnt vmcnt(4)" ::: "memory");
  __builtin_amdgcn_s_barrier();
  __builtin_amdgcn_sched_barrier(0);

  for (int kt = 0; kt < 16; kt++){
    int cur = kt & 1;
    s16x8 ak[2][4], av[2][4];
    #pragma unroll
    for (int mt = 0; mt < 2; mt++){
      int r0 = mt*32 + q5;
      int sw = r0 & 7;
      #pragma unroll
      for (int dk = 0; dk < 4; dk++)
        ak[mt][dk] = *(const s16x8*)&Ks[cur][r0*64 + (((2*dk + hi2) ^ sw)*8)];
      #pragma unroll
      for (int ks = 0; ks < 4; ks++)
        av[mt][ks] = *(const s16x8*)&Vs[cur][r0*64 + (((2*ks + hi2) ^ sw)*8)];
    }
    asm volatile("s_waitcnt lgkmcnt(0)" ::: "memory");
    __builtin_amdgcn_sched_barrier(0);
    __builtin_amdgcn_s_barrier();
    __builtin_amdgcn_sched_barrier(0);
    if (kt < 14) STAGE(cur, kt+2);

    f32x16 sacc[2];
    #pragma unroll
    for (int mt = 0; mt < 2; mt++){
      f32x16 acc;
      #pragma unroll
      for (int r = 0; r < 16; r++) acc[r] = 0.f;
      #pragma unroll
      for (int dk = 0; dk < 4; dk++)
        acc = __builtin_amdgcn_mfma_f32_32x32x16_bf16(ak[mt][dk], bq[dk], acc, 0,0,0);
      sacc[mt] = acc;
    }

    float p[2][16];
    float rs = 0.f;
    #pragma unroll
    for (int mt = 0; mt < 2; mt++)
      #pragma unroll
      for (int r = 0; r < 16; r++){
        float e = __expf(sacc[mt][r]);
        p[mt][r] = e; rs += e;
      }
    rs += __shfl_xor(rs, 32, 64);
    l_ += rs;

    unsigned wds[4][4];
    #pragma unroll
    for (int ks = 0; ks < 4; ks++){
      const int mt = ks >> 1, base = (ks & 1)*8;
      unsigned a0 = cvtpk(p[mt][base+0], p[mt][base+1]);
      unsigned b0 = cvtpk(p[mt][base+4], p[mt][base+5]);
      asm("v_permlane32_swap_b32 %0, %1" : "+v"(a0), "+v"(b0));
      unsigned a1 = cvtpk(p[mt][base+2], p[mt][base+3]);
      unsigned b1 = cvtpk(p[mt][base+6], p[mt][base+7]);
      asm("v_permlane32_swap_b32 %0, %1" : "+v"(a1), "+v"(b1));
      wds[ks][0] = a0; wds[ks][1] = a1; wds[ks][2] = b0; wds[ks][3] = b1;
    }

    #pragma unroll
    for (int ks = 0; ks < 4; ks++){
      union { unsigned u[4]; s16x8 v; } bp;
      bp.u[0] = wds[ks][0]; bp.u[1] = wds[ks][1];
      bp.u[2] = wds[ks][2]; bp.u[3] = wds[ks][3];
      #pragma unroll
      for (int mt = 0; mt < 2; mt++)
        o[mt] = __builtin_amdgcn_mfma_f32_32x32x16_bf16(av[mt][ks], bp.v, o[mt], 0,0,0);
    }

    if (kt < 15){
      if (kt < 14) asm volatile("s_waitcnt vmcnt(4)" ::: "memory");
      else         asm volatile("s_waitcnt vmcnt(0)" ::: "memory");
      __builtin_amdgcn_s_barrier();
      __builtin_amdgcn_sched_barrier(0);
    }
  }
  #undef STAGE

  __builtin_amdgcn_s_barrier();
  float inv = 1.f / l_;
  u16* ob = ((w < 2) ? (u16*)Ks : (u16*)Vs) + (w & 1)*2304;
  #pragma unroll
  for (int mt = 0; mt < 2; mt++)
    #pragma unroll
    for (int g = 0; g < 4; g++)
      #pragma unroll
      for (int p2 = 0; p2 < 2; p2++){
        unsigned wd = cvtpk(o[mt][g*4 + p2*2]*inv, o[mt][g*4 + p2*2 + 1]*inv);
        int d0 = mt*32 + g*8 + hi2*4 + p2*2;
        *(unsigned*)&ob[q5*72 + d0] = wd;
      }
  asm volatile("s_waitcnt lgkmcnt(0)" ::: "memory");
  __builtin_amdgcn_sched_barrier(0);
  int r2 = l >> 1, cb = (l & 1)*32;
  size_t row = rowbase + qt*128 + w*32 + r2;
  #pragma unroll
  for (int c = 0; c < 4; c++){
    uint4 v = *(uint4*)&ob[r2*72 + cb + c*8];
    *(uint4*)&ctx[row*512 + h*64 + cb + c*8] = v;
  }
}

// ---------------- LN2 + ACT mix + next-step halting update (4 rows / 256-thr block) ----------------
__global__ __launch_bounds__(256) void ln2mix_kernel(
    const u16* __restrict__ yb, const u16* __restrict__ o2b,
    const float2* __restrict__ parts1,
    const float* __restrict__ g1, const float* __restrict__ be1,
    const float* __restrict__ g, const float* __restrict__ bt,
    const float* __restrict__ aw, const float* __restrict__ ab,
    float* __restrict__ st, u16* __restrict__ stb,
    float* __restrict__ hp, float* __restrict__ rem, float* __restrict__ uw,
    unsigned* __restrict__ tfact_next, unsigned* __restrict__ tfchg_next){
  int lane = threadIdx.x & 63;
  int row = blockIdx.x*4 + (threadIdx.x >> 6);
  float u = uw[row];
  if (u == 0.f) return;              // frozen at this step's entry: exact no-op (per-wave)
  size_t base = (size_t)row*512 + lane*8;
  // row stats from wo partials (16 consecutive strips of this row)
  float2 pp = parts1[(size_t)row*16 + (lane & 15)];
  float ps = pp.x, pq = pp.y;
  #pragma unroll
  for (int msk=1;msk<16;msk<<=1){ ps += __shfl_xor(ps,msk,64); pq += __shfl_xor(pq,msk,64); }
  float mu1 = ps*(1.f/512.f);
  float var1 = pq*(1.f/512.f) - mu1*mu1;
  float rstd1 = rsqrtf(fmaxf(var1, 0.f) + 1e-6f);
  int c0 = lane*8;
  float v[8], sv[8];
  {
    u16x8 y8 = *(const u16x8*)(yb + base);
    u16x8 o8 = *(const u16x8*)(o2b + base);
    const float4* sp = (const float4*)(st + base);
    float4 s0 = sp[0], s1f = sp[1];
    #pragma unroll
    for (int j=0;j<8;j++){
      float out1 = (b2f(y8[j]) - mu1)*rstd1*g1[c0+j] + be1[c0+j];
      v[j] = out1 + b2f(o8[j]);
    }
    sv[0]=s0.x; sv[1]=s0.y; sv[2]=s0.z; sv[3]=s0.w;
    sv[4]=s1f.x; sv[5]=s1f.y; sv[6]=s1f.z; sv[7]=s1f.w;
  }
  float sum=0.f, sq=0.f;
  #pragma unroll
  for (int j=0;j<8;j++){ sum += v[j]; sq += v[j]*v[j]; }
  sum = wred_sum(sum); sq = wred_sum(sq);
  float mean = sum*(1.f/512.f);
  float var  = sq*(1.f/512.f) - mean*mean;
  float rstd = rsqrtf(fmaxf(var, 0.f) + 1e-6f);
  float um1 = 1.f - u;
  float z[8]; u16x8 ob;
  #pragma unroll
  for (int j=0;j<8;j++){
    float y = (v[j]-mean)*rstd*g[c0+j] + bt[c0+j];
    z[j] = y*u + sv[j]*um1;
    ob[j] = f2b(z[j]);
  }
  float4* op = (float4*)(st + base);
  op[0] = make_float4(z[0],z[1],z[2],z[3]);
  op[1] = make_float4(z[4],z[5],z[6],z[7]);
  *(u16x8*)(stb + base) = ob;
  const float4* wp = (const float4*)aw + (size_t)lane*2;
  float4 w0 = wp[0], w1 = wp[1];
  float d = z[0]*w0.x + z[1]*w0.y + z[2]*w0.z + z[3]*w0.w
          + z[4]*w1.x + z[5]*w1.y + z[6]*w1.z + z[7]*w1.w;
  d = wred_sum(d);
  if (lane == 0){
    float t = d + ab[0];
    float p = 1.f / (1.f + expf(-t));
    float h = hp[row], r = rem[row];
    bool active_next = (h < 1.f);    // uw_{s+1} != 0 iff this (pre-update) h < 1
    float still = active_next ? 1.f : 0.f;
    float cand  = h + p*still;
    float nh  = (cand > 0.99f)  ? still : 0.f;
    float st2 = (cand <= 0.99f) ? still : 0.f;
    h += p*st2;
    r += nh*(1.f - h);
    h += nh*r;
    hp[row] = h; rem[row] = r;
    uw[row] = p*st2 + nh*r;
    // idempotent flag set: plain stores (fresh per-step slot, zeroed once at init)
    tfchg_next[row >> 7] = 1u;
    if (active_next) tfact_next[row >> 7] = 1u;
  }
}

// ---------------- host launch ----------------
extern "C" void kernel_launch(void* const* d_in, const int* in_sizes, int n_in,
                              void* d_out, int out_size, void* d_ws, size_t ws_size,
                              hipStream_t stream){
  const float* x     = (const float*)d_in[0];
  const float* wq    = (const float*)d_in[1];
  const float* bq    = (const float*)d_in[2];
  const float* wk    = (const float*)d_in[3];
  const float* bk    = (const float*)d_in[4];
  const float* wv    = (const float*)d_in[5];
  const float* bv    = (const float*)d_in[6];
  const float* wo    = (const float*)d_in[7];
  const float* bo    = (const float*)d_in[8];
  const float* w1    = (const float*)d_in[9];
  const float* b1    = (const float*)d_in[10];
  const float* lnf_g = (const float*)d_in[11];
  const float* lnf_b = (const float*)d_in[12];
  const float* w2    = (const float*)d_in[13];
  const float* b2    = (const float*)d_in[14];
  const float* ln1_g = (const float*)d_in[15];
  const float* ln1_b = (const float*)d_in[16];
  const float* ln2_g = (const float*)d_in[17];
  const float* ln2_b = (const float*)d_in[18];
  const float* aw    = (const float*)d_in[19];
  const float* ab    = (const float*)d_in[20];
  float* st = (float*)d_out;

  char* cur = (char*)d_ws;
  auto alloc = [&](size_t n){ void* p = cur; cur += (n + 255) & ~(size_t)255; return p; };
  u16*  wqkv_t = (u16*)alloc((size_t)1536*512*2);
  u16*  wo_t   = (u16*)alloc((size_t)512*512*2);
  u16*  w1_t   = (u16*)alloc((size_t)2048*512*2);   // ln1_g-scaled
  u16*  w2_t   = (u16*)alloc((size_t)512*2048*2);   // lnf_g-scaled
  float* bqkv  = (float*)alloc(1536*4);
  float* G1    = (float*)alloc(2048*4);
  float* C1    = (float*)alloc(2048*4);
  float* G2    = (float*)alloc(512*4);
  float* C2    = (float*)alloc(512*4);
  float* pg    = (float*)alloc((size_t)16384*4);
  float* pc    = (float*)alloc((size_t)16384*4);
  u16*  stb    = (u16*)alloc((size_t)M_*512*2);
  u16*  qkv    = (u16*)alloc((size_t)M_*1536*2);
  u16*  vt     = (u16*)alloc((size_t)M_*512*2);     // persistent transposed V
  u16*  ctx    = (u16*)alloc((size_t)M_*512*2);
  u16*  yb     = (u16*)alloc((size_t)M_*512*2);
  u16*  o2b    = (u16*)alloc((size_t)M_*512*2);
  u16*  hbuf   = (u16*)alloc((size_t)M_*2048*2);
  float2* parts1 = (float2*)alloc((size_t)M_*16*8);   // [row][16]
  float2* parts2 = (float2*)alloc((size_t)M_*64*8);   // [row][64]
  float* halt  = (float*)alloc((size_t)3*M_*4);
  unsigned* flags = (unsigned*)alloc(896*4);        // 7 steps x {act[64], chg[64]}
  float* hp = halt, *rem = halt + M_, *uw = halt + 2*M_;

  prep_kernel<<<2048, 256, 0, stream>>>(x, aw, ab, st, stb, hp, rem, uw);
  packb_kernel<<<6, 256, 0, stream>>>(bq, bk, bv, bqkv, flags);
  tcast_kernel<<<64,  256, 0, stream>>>(wq, wqkv_t,            512, 512, nullptr);
  tcast_kernel<<<64,  256, 0, stream>>>(wk, wqkv_t + 512*512,  512, 512, nullptr);
  tcast_kernel<<<64,  256, 0, stream>>>(wv, wqkv_t + 1024*512, 512, 512, nullptr);
  tcast_kernel<<<64,  256, 0, stream>>>(wo, wo_t, 512, 512, nullptr);
  tcast_kernel<<<256, 256, 0, stream>>>(w1, w1_t, 512, 2048, ln1_g);
  tcast_kernel<<<256, 256, 0, stream>>>(w2, w2_t, 2048, 512, lnf_g);
  gcpart_kernel<<<dim3(8, 8),  256, 0, stream>>>(w1, ln1_g, ln1_b, pg, pc, 2048);
  gcred_kernel<<<8, 256, 0, stream>>>(pg, pc, G1, C1, 8, 2048);
  gcpart_kernel<<<dim3(32, 2), 256, 0, stream>>>(w2, lnf_g, lnf_b, pg, pc, 512);
  gcred_kernel<<<2, 256, 0, stream>>>(pg, pc, G2, C2, 32, 512);

  for (int s = 0; s < STEPS_; s++){
    unsigned* act_c = flags + s*128;
    unsigned* chg_c = act_c + 64;
    unsigned* act_n = flags + (s+1)*128;
    unsigned* chg_n = act_n + 64;
    gemm128_kernel<1><<<64*12, 512, 0, stream>>>(stb, wqkv_t, bqkv, qkv, 12, 512, 1536,
                                                 vt, nullptr, 0, 0.f, nullptr, nullptr, nullptr,
                                                 nullptr, chg_c, act_c);
    attn_kernel<<<512, 256, 0, stream>>>(qkv, vt, ctx, act_c);
    gemm128_kernel<3><<<64*4, 512, 0, stream>>>(ctx, wo_t, bo, yb, 4, 512, 512,
                                                nullptr, nullptr, 0, 0.f, nullptr, nullptr, parts1,
                                                stb, act_c, nullptr);
    gemm128_kernel<4><<<64*16, 512, 0, stream>>>(yb, w1_t, b1, hbuf, 16, 512, 2048,
                                                 nullptr, parts1, 16, 1.f/512.f, G1, C1, parts2,
                                                 nullptr, act_c, nullptr);
    gemm128_kernel<5><<<64*4, 512, 0, stream>>>(hbuf, w2_t, b2, o2b, 4, 2048, 512,
                                                nullptr, parts2, 64, 1.f/2048.f, G2, C2, nullptr,
                                                nullptr, act_c, nullptr);
    ln2mix_kernel<<<M_/4, 256, 0, stream>>>(yb, o2b, parts1, ln1_g, ln1_b, ln2_g, ln2_b,
                                            aw, ab, st, stb, hp, rem, uw, act_n, chg_n);
  }
}